// Round 6
// baseline (381.088 us; speedup 1.0000x reference)
//
#include <hip/hip_runtime.h>
#include <math.h>

// Problem constants (reference: B=8, N=2048, C=256, W=256)
#define Bb 8
#define Nn 2048
#define Cc 256
#define Ww 256
#define Mtot (Bb*Nn)   // 16384

typedef __attribute__((ext_vector_type(8))) short bf16x8;
typedef __attribute__((ext_vector_type(8))) ushort us16x8;
typedef __attribute__((ext_vector_type(4))) float f32x4;

__device__ __forceinline__ ushort bf16_rne(float f) {
    uint u = __float_as_uint(f);
    return (ushort)((u + 0x7FFFu + ((u >> 16) & 1u)) >> 16);
}
__device__ __forceinline__ float bf16_to_f32(ushort h) {
    return __uint_as_float(((uint)h) << 16);
}
__device__ __forceinline__ ushort u4get(ushort4 v, int c) {
    return c == 0 ? v.x : (c == 1 ? v.y : (c == 2 ? v.z : v.w));
}
// XOR chunk-swizzled LDS index for [row][32-ushort] tiles (16B chunks).
// Write AND read must use the same map. (row>>2)&3 varies within both the
// staging-write lanes (i-quad id) and the frag-read lanes (lr>>2) -> banks spread.
__device__ __forceinline__ int lidx(int row, int chunk) {
    return row * 32 + (((chunk ^ ((row >> 2) & 3))) << 3);
}

// ---------------------------------------------------------------------------
// Kernel 1: fused QKV projection. r = relu(x·Wᵀ + b). (unchanged, proven)
// ---------------------------------------------------------------------------
__global__ __launch_bounds__(256) void qkv_proj_kernel(
    const float* __restrict__ x,
    const float* __restrict__ Wq, const float* __restrict__ bq,
    const float* __restrict__ Wk, const float* __restrict__ bk,
    const float* __restrict__ Wv, const float* __restrict__ bv,
    float* __restrict__ v32,
    ushort* __restrict__ qhi, ushort* __restrict__ qlo,
    ushort* __restrict__ khi, ushort* __restrict__ klo)
{
    __shared__ float xs[16][132];
    __shared__ float ws[16][68];

    const int tid = threadIdx.x;
    const int tn = tid & 15;
    const int tm = tid >> 4;
    const int m0 = blockIdx.x * 128;
    const int nt = blockIdx.y;
    const int which = nt >> 2;
    const int w0 = (nt & 3) * 64;

    const float* Wm = (which == 0) ? Wq : ((which == 1) ? Wk : Wv);
    const float* bm = (which == 0) ? bq : ((which == 1) ? bk : bv);

    float acc[8][4];
    #pragma unroll
    for (int i = 0; i < 8; ++i)
        #pragma unroll
        for (int j = 0; j < 4; ++j) acc[i][j] = 0.f;

    for (int kc = 0; kc < Cc; kc += 16) {
        #pragma unroll
        for (int l = 0; l < 2; ++l) {
            int s = tid + l * 256;
            int r = s >> 2, c4 = s & 3;
            float4 tv = *(const float4*)(x + (size_t)(m0 + r) * Cc + kc + c4 * 4);
            xs[c4*4+0][r] = tv.x; xs[c4*4+1][r] = tv.y;
            xs[c4*4+2][r] = tv.z; xs[c4*4+3][r] = tv.w;
        }
        {
            int r = tid >> 2, c4 = tid & 3;
            float4 tv = *(const float4*)(Wm + (size_t)(w0 + r) * Cc + kc + c4 * 4);
            ws[c4*4+0][r] = tv.x; ws[c4*4+1][r] = tv.y;
            ws[c4*4+2][r] = tv.z; ws[c4*4+3][r] = tv.w;
        }
        __syncthreads();
        #pragma unroll
        for (int kk = 0; kk < 16; ++kk) {
            float4 a0 = *(const float4*)&xs[kk][tm*4];
            float4 a1 = *(const float4*)&xs[kk][tm*4 + 64];
            float4 b0 = *(const float4*)&ws[kk][tn*4];
            float a[8] = {a0.x,a0.y,a0.z,a0.w,a1.x,a1.y,a1.z,a1.w};
            float b[4] = {b0.x,b0.y,b0.z,b0.w};
            #pragma unroll
            for (int i = 0; i < 8; ++i)
                #pragma unroll
                for (int j = 0; j < 4; ++j) acc[i][j] += a[i] * b[j];
        }
        __syncthreads();
    }

    float4 bias = *(const float4*)(bm + w0 + tn*4);
    #pragma unroll
    for (int i = 0; i < 8; ++i) {
        int m = m0 + tm*4 + (i & 3) + (i >> 2) * 64;
        float rr0 = fmaxf(acc[i][0] + bias.x, 0.f);
        float rr1 = fmaxf(acc[i][1] + bias.y, 0.f);
        float rr2 = fmaxf(acc[i][2] + bias.z, 0.f);
        float rr3 = fmaxf(acc[i][3] + bias.w, 0.f);
        size_t o = (size_t)m * Ww + w0 + tn*4;
        if (which == 2) {
            float4 r; r.x = rr0; r.y = rr1; r.z = rr2; r.w = rr3;
            *(float4*)(v32 + o) = r;
        } else {
            ushort4 h, l;
            h.x = bf16_rne(rr0); l.x = bf16_rne(rr0 - bf16_to_f32(h.x));
            h.y = bf16_rne(rr1); l.y = bf16_rne(rr1 - bf16_to_f32(h.y));
            h.z = bf16_rne(rr2); l.z = bf16_rne(rr2 - bf16_to_f32(h.z));
            h.w = bf16_rne(rr3); l.w = bf16_rne(rr3 - bf16_to_f32(h.w));
            ushort* hp = (which == 0) ? qhi : khi;
            ushort* lp = (which == 0) ? qlo : klo;
            *(ushort4*)(hp + o) = h;
            *(ushort4*)(lp + o) = l;
        }
    }
}

// ---------------------------------------------------------------------------
// Kernel 2: STh/STl[b][j][i] = split-bf16( scale * sum_w k[b,j,w]*q[b,i,w] )
// Proven MFMA body; C-write emits split bf16 (softmax + PV never touch fp32).
// ---------------------------------------------------------------------------
__global__ __launch_bounds__(256) void scores_mfma_kernel(
    const ushort* __restrict__ qhi, const ushort* __restrict__ qlo,
    const ushort* __restrict__ khi, const ushort* __restrict__ klo,
    ushort* __restrict__ sth, ushort* __restrict__ stl)
{
    __shared__ ushort lkh[4096], lkl[4096], lqh[4096], lql[4096];

    const int tid = threadIdx.x;
    const int i0 = blockIdx.x * 128;
    const int j0 = blockIdx.y * 128;
    const int b  = blockIdx.z;

    const ushort* kh = khi + ((size_t)b * Nn + j0) * Ww;
    const ushort* kl = klo + ((size_t)b * Nn + j0) * Ww;
    const ushort* qh = qhi + ((size_t)b * Nn + i0) * Ww;
    const ushort* ql = qlo + ((size_t)b * Nn + i0) * Ww;

    const int wave = tid >> 6, lane = tid & 63;
    const int wy = wave >> 1, wx = wave & 1;
    const int lrow = lane & 15, lg = lane >> 4;

    f32x4 acc[4][4];
    #pragma unroll
    for (int a = 0; a < 4; ++a)
        #pragma unroll
        for (int c = 0; c < 4; ++c) acc[a][c] = (f32x4){0.f, 0.f, 0.f, 0.f};

    const int cg = tid & 3;
    const int cr0 = tid >> 2;

    for (int kc = 0; kc < Ww; kc += 32) {
        #pragma unroll
        for (int h = 0; h < 2; ++h) {
            int r = cr0 + h * 64;
            int gg = cg ^ ((r >> 1) & 3);
            int li = r * 32 + gg * 8;
            size_t go = (size_t)r * Ww + kc + cg * 8;
            *(bf16x8*)&lkh[li] = *(const bf16x8*)(kh + go);
            *(bf16x8*)&lkl[li] = *(const bf16x8*)(kl + go);
            *(bf16x8*)&lqh[li] = *(const bf16x8*)(qh + go);
            *(bf16x8*)&lql[li] = *(const bf16x8*)(ql + go);
        }
        __syncthreads();

        bf16x8 ah[4], al[4], bh[4], bl[4];
        #pragma unroll
        for (int t = 0; t < 4; ++t) {
            int ra = wy * 64 + t * 16 + lrow;
            int ia = ra * 32 + ((lg ^ ((ra >> 1) & 3)) * 8);
            ah[t] = *(const bf16x8*)&lkh[ia];
            al[t] = *(const bf16x8*)&lkl[ia];
            int rb = wx * 64 + t * 16 + lrow;
            int ib = rb * 32 + ((lg ^ ((rb >> 1) & 3)) * 8);
            bh[t] = *(const bf16x8*)&lqh[ib];
            bl[t] = *(const bf16x8*)&lql[ib];
        }
        #pragma unroll
        for (int jt = 0; jt < 4; ++jt)
            #pragma unroll
            for (int it = 0; it < 4; ++it) {
                acc[jt][it] = __builtin_amdgcn_mfma_f32_16x16x32_bf16(ah[jt], bh[it], acc[jt][it], 0, 0, 0);
                acc[jt][it] = __builtin_amdgcn_mfma_f32_16x16x32_bf16(ah[jt], bl[it], acc[jt][it], 0, 0, 0);
                acc[jt][it] = __builtin_amdgcn_mfma_f32_16x16x32_bf16(al[jt], bh[it], acc[jt][it], 0, 0, 0);
            }
        __syncthreads();
    }

    const float scale = 0.02209708691207961f;  // 1/sqrt(2048)
    ushort* shb = sth + (size_t)b * Nn * Nn;
    ushort* slb = stl + (size_t)b * Nn * Nn;
    #pragma unroll
    for (int jt = 0; jt < 4; ++jt) {
        int jbase = j0 + wy * 64 + jt * 16 + lg * 4;
        #pragma unroll
        for (int it = 0; it < 4; ++it) {
            int i = i0 + wx * 64 + it * 16 + lrow;
            #pragma unroll
            for (int rg = 0; rg < 4; ++rg) {
                float val = acc[jt][it][rg] * scale;
                ushort h = bf16_rne(val);
                size_t o = (size_t)(jbase + rg) * Nn + i;
                shb[o] = h;
                slb[o] = bf16_rne(val - bf16_to_f32(h));
            }
        }
    }
}

// ---------------------------------------------------------------------------
// Kernel 2.5: vT split-transpose. v32[b][j][w] f32 -> vthi/vtlo[b][w][j].
// (unchanged, proven)
// ---------------------------------------------------------------------------
__global__ __launch_bounds__(256) void vt_kernel(
    const float* __restrict__ v32,
    ushort* __restrict__ vthi, ushort* __restrict__ vtlo)
{
    __shared__ ushort Thi[64*66], Tlo[64*66];
    const int tid = threadIdx.x;
    const int j0 = blockIdx.x * 64;
    const int w0 = blockIdx.y * 64;
    const int b  = blockIdx.z;
    const float* vb = v32 + (size_t)b * Nn * Ww;

    #pragma unroll
    for (int r = 0; r < 4; ++r) {
        int j  = (tid >> 4) + r * 16;
        int wl = (tid & 15) * 4;
        float4 tv = *(const float4*)(vb + (size_t)(j0 + j) * Ww + w0 + wl);
        float f[4] = {tv.x, tv.y, tv.z, tv.w};
        #pragma unroll
        for (int c = 0; c < 4; ++c) {
            ushort h = bf16_rne(f[c]);
            Thi[(wl + c) * 66 + j] = h;
            Tlo[(wl + c) * 66 + j] = bf16_rne(f[c] - bf16_to_f32(h));
        }
    }
    __syncthreads();
    {
        int wl = tid >> 2, jc = (tid & 3) * 16;
        size_t go = ((size_t)b * Ww + w0 + wl) * Nn + j0 + jc;
        uint tH[8], tL[8];
        #pragma unroll
        for (int u = 0; u < 8; ++u) {
            tH[u] = *(const uint*)&Thi[wl * 66 + jc + u * 2];
            tL[u] = *(const uint*)&Tlo[wl * 66 + jc + u * 2];
        }
        #pragma unroll
        for (int u = 0; u < 2; ++u) {
            uint4 hh; hh.x = tH[u*4+0]; hh.y = tH[u*4+1]; hh.z = tH[u*4+2]; hh.w = tH[u*4+3];
            uint4 ll; ll.x = tL[u*4+0]; ll.y = tL[u*4+1]; ll.z = tL[u*4+2]; ll.w = tL[u*4+3];
            *(uint4*)(vthi + go + u * 8) = hh;
            *(uint4*)(vtlo + go + u * 8) = ll;
        }
    }
}

// ---------------------------------------------------------------------------
// Kernel 3: softmax over i (rows of ST). Split-bf16 in/out, in place.
// grid (2048, 8), block 256.
// ---------------------------------------------------------------------------
__global__ __launch_bounds__(256) void softmax_kernel(
    ushort* __restrict__ sth, ushort* __restrict__ stl)
{
    const int j = blockIdx.x;
    const int b = blockIdx.y;
    ushort* rh = sth + ((size_t)b * Nn + j) * Nn;
    ushort* rl = stl + ((size_t)b * Nn + j) * Nn;
    const int tid = threadIdx.x;

    us16x8 hv = *(const us16x8*)(rh + tid * 8);
    us16x8 lv = *(const us16x8*)(rl + tid * 8);

    float s[8];
    #pragma unroll
    for (int e = 0; e < 8; ++e)
        s[e] = bf16_to_f32((ushort)hv[e]) + bf16_to_f32((ushort)lv[e]);

    float vmax = s[0];
    #pragma unroll
    for (int e = 1; e < 8; ++e) vmax = fmaxf(vmax, s[e]);
    #pragma unroll
    for (int off = 32; off > 0; off >>= 1)
        vmax = fmaxf(vmax, __shfl_xor(vmax, off));

    __shared__ float redm[4];
    __shared__ float reds[4];
    const int wid = tid >> 6, lane = tid & 63;
    if (lane == 0) redm[wid] = vmax;
    __syncthreads();
    vmax = fmaxf(fmaxf(redm[0], redm[1]), fmaxf(redm[2], redm[3]));

    float p[8];
    float sum = 0.f;
    #pragma unroll
    for (int e = 0; e < 8; ++e) { p[e] = __expf(s[e] - vmax); sum += p[e]; }
    #pragma unroll
    for (int off = 32; off > 0; off >>= 1)
        sum += __shfl_xor(sum, off);
    if (lane == 0) reds[wid] = sum;
    __syncthreads();
    sum = (reds[0] + reds[1]) + (reds[2] + reds[3]);

    const float inv = 1.0f / sum;
    us16x8 oh, ol;
    #pragma unroll
    for (int e = 0; e < 8; ++e) {
        float pv = p[e] * inv;
        ushort h = bf16_rne(pv);
        oh[e] = (short)h;
        ol[e] = (short)bf16_rne(pv - bf16_to_f32(h));
    }
    *(us16x8*)(rh + tid * 8) = oh;
    *(us16x8*)(rl + tid * 8) = ol;
}

// ---------------------------------------------------------------------------
// Kernel 4: PV via split-bf16 MFMA + K-split atomics.
// out[b,i,w] += sum_j P[j][i]*v[j][w]  (q added by qadd_kernel; out pre-zeroed)
// Block tile 128i x 128w, K-chunk 512 (ksplit 4). 256 thr = 4 waves (2x2),
// wave tile 64x64 (16 frag-reads / 48 MFMA). XOR chunk swizzle on all LDS
// tiles, same map on stage-write and frag-read.
// grid (16 i, 2 wt x 4 kz, 8 b) = 1024 blocks = 4 blocks/CU.
// ---------------------------------------------------------------------------
__global__ __launch_bounds__(256) void pv_mfma_kernel(
    const ushort* __restrict__ ph, const ushort* __restrict__ pl,
    const ushort* __restrict__ vthi, const ushort* __restrict__ vtlo,
    float* __restrict__ out)
{
    __shared__ ushort Ah[4096], Al[4096], Bh[4096], Bl[4096];   // 32 KB

    const int tid = threadIdx.x;
    const int i0 = blockIdx.x * 128;
    const int wt = blockIdx.y & 1, kz = blockIdx.y >> 1;
    const int w0 = wt * 128;
    const int b  = blockIdx.z;

    const ushort* phb = ph + (size_t)b * Nn * Nn;
    const ushort* plb = pl + (size_t)b * Nn * Nn;
    const ushort* vhb = vthi + (size_t)b * Ww * Nn;
    const ushort* vlb = vtlo + (size_t)b * Ww * Nn;

    const int wave = tid >> 6, lane = tid & 63;
    const int wy = wave >> 1, wx = wave & 1;    // i-half / w-half
    const int lr = lane & 15, lg = lane >> 4;

    f32x4 acc[4][4];
    #pragma unroll
    for (int a = 0; a < 4; ++a)
        #pragma unroll
        for (int c = 0; c < 4; ++c) acc[a][c] = (f32x4){0.f, 0.f, 0.f, 0.f};

    const int aj4 = tid >> 5;        // 0..7  : j-quad (A staging)
    const int ai4 = tid & 31;        // 0..31 : i-quad group
    const int bwr = tid >> 2;        // 0..63 : w row (B staging, +64 second pass)
    const int bcg = tid & 3;         // j-chunk

    for (int ks = 0; ks < 16; ++ks) {
        const int kc = kz * 512 + ks * 32;

        // ---- stage A: P[j][i] tile (32j x 128i) -> transposed LDS [i][j] ----
        ushort4 hv[4], lv[4];
        #pragma unroll
        for (int d = 0; d < 4; ++d) {
            size_t go = (size_t)(kc + aj4 * 4 + d) * Nn + i0 + ai4 * 4;
            hv[d] = *(const ushort4*)(phb + go);
            lv[d] = *(const ushort4*)(plb + go);
        }
        #pragma unroll
        for (int c = 0; c < 4; ++c) {
            const int il = ai4 * 4 + c;
            const int base = il * 32 + (((aj4 >> 1) ^ ((il >> 2) & 3)) << 3) + (aj4 & 1) * 4;
            ushort4 th, tl;
            th.x = u4get(hv[0], c); th.y = u4get(hv[1], c);
            th.z = u4get(hv[2], c); th.w = u4get(hv[3], c);
            tl.x = u4get(lv[0], c); tl.y = u4get(lv[1], c);
            tl.z = u4get(lv[2], c); tl.w = u4get(lv[3], c);
            *(ushort4*)&Ah[base] = th;
            *(ushort4*)&Al[base] = tl;
        }
        // ---- stage B: vT[w][j] tile (128w x 32j), direct bf16x8 copies ----
        #pragma unroll
        for (int p = 0; p < 2; ++p) {
            const int wl = bwr + p * 64;
            size_t go = (size_t)(w0 + wl) * Nn + kc + bcg * 8;
            *(bf16x8*)&Bh[lidx(wl, bcg)] = *(const bf16x8*)(vhb + go);
            *(bf16x8*)&Bl[lidx(wl, bcg)] = *(const bf16x8*)(vlb + go);
        }
        __syncthreads();

        bf16x8 afh[4], afl[4], bfh[4], bfl[4];
        #pragma unroll
        for (int t = 0; t < 4; ++t) {
            const int ar = wy * 64 + t * 16 + lr;
            afh[t] = *(const bf16x8*)&Ah[lidx(ar, lg)];
            afl[t] = *(const bf16x8*)&Al[lidx(ar, lg)];
            const int br = wx * 64 + t * 16 + lr;
            bfh[t] = *(const bf16x8*)&Bh[lidx(br, lg)];
            bfl[t] = *(const bf16x8*)&Bl[lidx(br, lg)];
        }
        #pragma unroll
        for (int ia = 0; ia < 4; ++ia)
            #pragma unroll
            for (int ib = 0; ib < 4; ++ib) {
                acc[ia][ib] = __builtin_amdgcn_mfma_f32_16x16x32_bf16(afh[ia], bfh[ib], acc[ia][ib], 0, 0, 0);
                acc[ia][ib] = __builtin_amdgcn_mfma_f32_16x16x32_bf16(afh[ia], bfl[ib], acc[ia][ib], 0, 0, 0);
                acc[ia][ib] = __builtin_amdgcn_mfma_f32_16x16x32_bf16(afl[ia], bfh[ib], acc[ia][ib], 0, 0, 0);
            }
        __syncthreads();
    }

    // epilogue: accumulate partials (ksplit) into pre-zeroed out
    #pragma unroll
    for (int ia = 0; ia < 4; ++ia) {
        const int ibase = i0 + wy * 64 + ia * 16 + lg * 4;
        #pragma unroll
        for (int ib = 0; ib < 4; ++ib) {
            const int w = w0 + wx * 64 + ib * 16 + lr;
            #pragma unroll
            for (int rg = 0; rg < 4; ++rg) {
                size_t gidx = ((size_t)(b * Nn + ibase + rg)) * Ww + w;
                atomicAdd(out + gidx, acc[ia][ib][rg]);
            }
        }
    }
}

// ---------------------------------------------------------------------------
// Kernel 5: out += q (reconstructed from split bf16). grid 4096, block 256.
// ---------------------------------------------------------------------------
__global__ __launch_bounds__(256) void qadd_kernel(
    const ushort* __restrict__ qhi, const ushort* __restrict__ qlo,
    float* __restrict__ out)
{
    const size_t g4 = ((size_t)blockIdx.x * 256 + threadIdx.x) * 4;
    ushort4 h = *(const ushort4*)(qhi + g4);
    ushort4 l = *(const ushort4*)(qlo + g4);
    float4 o = *(const float4*)(out + g4);
    o.x += bf16_to_f32(h.x) + bf16_to_f32(l.x);
    o.y += bf16_to_f32(h.y) + bf16_to_f32(l.y);
    o.z += bf16_to_f32(h.z) + bf16_to_f32(l.z);
    o.w += bf16_to_f32(h.w) + bf16_to_f32(l.w);
    *(float4*)(out + g4) = o;
}

// ---------------------------------------------------------------------------
// Launch. ws: v32 f32 [16MB] | qhi,qlo,khi,klo bf16 [4x8MB] | STh [64MB] |
// STl [64MB] = 176 MiB (unchanged). vthi/vtlo reuse khi/klo after scores.
// ---------------------------------------------------------------------------
extern "C" void kernel_launch(void* const* d_in, const int* in_sizes, int n_in,
                              void* d_out, int out_size, void* d_ws, size_t ws_size,
                              hipStream_t stream) {
    const float* x  = (const float*)d_in[0];
    const float* Wq = (const float*)d_in[1];
    const float* bq = (const float*)d_in[2];
    const float* Wk = (const float*)d_in[3];
    const float* bk = (const float*)d_in[4];
    const float* Wv = (const float*)d_in[5];
    const float* bv = (const float*)d_in[6];
    // d_in[7] = valid_len (unused by the reference forward)
    float* out = (float*)d_out;

    float*  v32 = (float*)d_ws;
    ushort* qhi = (ushort*)(v32 + (size_t)Mtot * Ww);
    ushort* qlo = qhi + (size_t)Mtot * Ww;
    ushort* khi = qlo + (size_t)Mtot * Ww;
    ushort* klo = khi + (size_t)Mtot * Ww;
    ushort* sth = klo + (size_t)Mtot * Ww;
    ushort* stl = sth + (size_t)Bb * Nn * Nn;
    ushort* vthi = khi;   // reuse after scores_mfma consumed k
    ushort* vtlo = klo;

    hipMemsetAsync(out, 0, (size_t)out_size * sizeof(float), stream);
    qkv_proj_kernel<<<dim3(128, 12), 256, 0, stream>>>(x, Wq, bq, Wk, bk, Wv, bv,
                                                       v32, qhi, qlo, khi, klo);
    scores_mfma_kernel<<<dim3(16, 16, 8), 256, 0, stream>>>(qhi, qlo, khi, klo, sth, stl);
    vt_kernel<<<dim3(32, 4, 8), 256, 0, stream>>>(v32, vthi, vtlo);
    softmax_kernel<<<dim3(Nn, Bb), 256, 0, stream>>>(sth, stl);
    pv_mfma_kernel<<<dim3(16, 8, 8), 256, 0, stream>>>(sth, stl, vthi, vtlo, out);
    qadd_kernel<<<dim3(4096), 256, 0, stream>>>(qhi, qlo, out);
}

// Round 7
// 345.668 us; speedup vs baseline: 1.1025x; 1.1025x over previous
//
#include <hip/hip_runtime.h>
#include <math.h>

// Problem constants (reference: B=8, N=2048, C=256, W=256)
#define Bb 8
#define Nn 2048
#define Cc 256
#define Ww 256
#define Mtot (Bb*Nn)   // 16384

typedef __attribute__((ext_vector_type(8))) short bf16x8;
typedef __attribute__((ext_vector_type(4))) float f32x4;

__device__ __forceinline__ ushort bf16_rne(float f) {
    uint u = __float_as_uint(f);
    return (ushort)((u + 0x7FFFu + ((u >> 16) & 1u)) >> 16);
}
__device__ __forceinline__ float bf16_to_f32(ushort h) {
    return __uint_as_float(((uint)h) << 16);
}

// ---------------------------------------------------------------------------
// Kernel 1: fused QKV projection. r = relu(x·Wᵀ + b). (unchanged, proven)
// ---------------------------------------------------------------------------
__global__ __launch_bounds__(256) void qkv_proj_kernel(
    const float* __restrict__ x,
    const float* __restrict__ Wq, const float* __restrict__ bq,
    const float* __restrict__ Wk, const float* __restrict__ bk,
    const float* __restrict__ Wv, const float* __restrict__ bv,
    float* __restrict__ v32,
    ushort* __restrict__ qhi, ushort* __restrict__ qlo,
    ushort* __restrict__ khi, ushort* __restrict__ klo)
{
    __shared__ float xs[16][132];
    __shared__ float ws[16][68];

    const int tid = threadIdx.x;
    const int tn = tid & 15;
    const int tm = tid >> 4;
    const int m0 = blockIdx.x * 128;
    const int nt = blockIdx.y;
    const int which = nt >> 2;
    const int w0 = (nt & 3) * 64;

    const float* Wm = (which == 0) ? Wq : ((which == 1) ? Wk : Wv);
    const float* bm = (which == 0) ? bq : ((which == 1) ? bk : bv);

    float acc[8][4];
    #pragma unroll
    for (int i = 0; i < 8; ++i)
        #pragma unroll
        for (int j = 0; j < 4; ++j) acc[i][j] = 0.f;

    for (int kc = 0; kc < Cc; kc += 16) {
        #pragma unroll
        for (int l = 0; l < 2; ++l) {
            int s = tid + l * 256;
            int r = s >> 2, c4 = s & 3;
            float4 tv = *(const float4*)(x + (size_t)(m0 + r) * Cc + kc + c4 * 4);
            xs[c4*4+0][r] = tv.x; xs[c4*4+1][r] = tv.y;
            xs[c4*4+2][r] = tv.z; xs[c4*4+3][r] = tv.w;
        }
        {
            int r = tid >> 2, c4 = tid & 3;
            float4 tv = *(const float4*)(Wm + (size_t)(w0 + r) * Cc + kc + c4 * 4);
            ws[c4*4+0][r] = tv.x; ws[c4*4+1][r] = tv.y;
            ws[c4*4+2][r] = tv.z; ws[c4*4+3][r] = tv.w;
        }
        __syncthreads();
        #pragma unroll
        for (int kk = 0; kk < 16; ++kk) {
            float4 a0 = *(const float4*)&xs[kk][tm*4];
            float4 a1 = *(const float4*)&xs[kk][tm*4 + 64];
            float4 b0 = *(const float4*)&ws[kk][tn*4];
            float a[8] = {a0.x,a0.y,a0.z,a0.w,a1.x,a1.y,a1.z,a1.w};
            float b[4] = {b0.x,b0.y,b0.z,b0.w};
            #pragma unroll
            for (int i = 0; i < 8; ++i)
                #pragma unroll
                for (int j = 0; j < 4; ++j) acc[i][j] += a[i] * b[j];
        }
        __syncthreads();
    }

    float4 bias = *(const float4*)(bm + w0 + tn*4);
    #pragma unroll
    for (int i = 0; i < 8; ++i) {
        int m = m0 + tm*4 + (i & 3) + (i >> 2) * 64;
        float rr0 = fmaxf(acc[i][0] + bias.x, 0.f);
        float rr1 = fmaxf(acc[i][1] + bias.y, 0.f);
        float rr2 = fmaxf(acc[i][2] + bias.z, 0.f);
        float rr3 = fmaxf(acc[i][3] + bias.w, 0.f);
        size_t o = (size_t)m * Ww + w0 + tn*4;
        if (which == 2) {
            float4 r; r.x = rr0; r.y = rr1; r.z = rr2; r.w = rr3;
            *(float4*)(v32 + o) = r;
        } else {
            ushort4 h, l;
            h.x = bf16_rne(rr0); l.x = bf16_rne(rr0 - bf16_to_f32(h.x));
            h.y = bf16_rne(rr1); l.y = bf16_rne(rr1 - bf16_to_f32(h.y));
            h.z = bf16_rne(rr2); l.z = bf16_rne(rr2 - bf16_to_f32(h.z));
            h.w = bf16_rne(rr3); l.w = bf16_rne(rr3 - bf16_to_f32(h.w));
            ushort* hp = (which == 0) ? qhi : khi;
            ushort* lp = (which == 0) ? qlo : klo;
            *(ushort4*)(hp + o) = h;
            *(ushort4*)(lp + o) = l;
        }
    }
}

// ---------------------------------------------------------------------------
// Kernel 2: E[b][i][j] = split-bf16( exp(scale * sum_w k[b,j,w]*q[b,i,w]) )
// + per-column partial sums D[j] = sum_i e (atomicAdd into pre-zeroed Dp).
// No max-subtraction: |s| <= scale*|q||k| ~ 14, exp(14)=1.2e6, fp32-safe;
// softmax normalization M cancels exactly, 1/D folded into v' (vt_kernel).
// Proven MFMA body; C-write now i-major (ushort4 j-runs, coalesced-ish).
// ---------------------------------------------------------------------------
__global__ __launch_bounds__(256) void scores_mfma_kernel(
    const ushort* __restrict__ qhi, const ushort* __restrict__ qlo,
    const ushort* __restrict__ khi, const ushort* __restrict__ klo,
    ushort* __restrict__ eh, ushort* __restrict__ el,
    float* __restrict__ dpart)
{
    __shared__ ushort lkh[4096], lkl[4096], lqh[4096], lql[4096];

    const int tid = threadIdx.x;
    const int i0 = blockIdx.x * 128;
    const int j0 = blockIdx.y * 128;
    const int b  = blockIdx.z;

    const ushort* kh = khi + ((size_t)b * Nn + j0) * Ww;
    const ushort* kl = klo + ((size_t)b * Nn + j0) * Ww;
    const ushort* qh = qhi + ((size_t)b * Nn + i0) * Ww;
    const ushort* ql = qlo + ((size_t)b * Nn + i0) * Ww;

    const int wave = tid >> 6, lane = tid & 63;
    const int wy = wave >> 1, wx = wave & 1;
    const int lrow = lane & 15, lg = lane >> 4;

    f32x4 acc[4][4];
    #pragma unroll
    for (int a = 0; a < 4; ++a)
        #pragma unroll
        for (int c = 0; c < 4; ++c) acc[a][c] = (f32x4){0.f, 0.f, 0.f, 0.f};

    const int cg = tid & 3;
    const int cr0 = tid >> 2;

    for (int kc = 0; kc < Ww; kc += 32) {
        #pragma unroll
        for (int h = 0; h < 2; ++h) {
            int r = cr0 + h * 64;
            int gg = cg ^ ((r >> 1) & 3);
            int li = r * 32 + gg * 8;
            size_t go = (size_t)r * Ww + kc + cg * 8;
            *(bf16x8*)&lkh[li] = *(const bf16x8*)(kh + go);
            *(bf16x8*)&lkl[li] = *(const bf16x8*)(kl + go);
            *(bf16x8*)&lqh[li] = *(const bf16x8*)(qh + go);
            *(bf16x8*)&lql[li] = *(const bf16x8*)(ql + go);
        }
        __syncthreads();

        bf16x8 ah[4], al[4], bh[4], bl[4];
        #pragma unroll
        for (int t = 0; t < 4; ++t) {
            int ra = wy * 64 + t * 16 + lrow;
            int ia = ra * 32 + ((lg ^ ((ra >> 1) & 3)) * 8);
            ah[t] = *(const bf16x8*)&lkh[ia];
            al[t] = *(const bf16x8*)&lkl[ia];
            int rb = wx * 64 + t * 16 + lrow;
            int ib = rb * 32 + ((lg ^ ((rb >> 1) & 3)) * 8);
            bh[t] = *(const bf16x8*)&lqh[ib];
            bl[t] = *(const bf16x8*)&lql[ib];
        }
        #pragma unroll
        for (int jt = 0; jt < 4; ++jt)
            #pragma unroll
            for (int it = 0; it < 4; ++it) {
                acc[jt][it] = __builtin_amdgcn_mfma_f32_16x16x32_bf16(ah[jt], bh[it], acc[jt][it], 0, 0, 0);
                acc[jt][it] = __builtin_amdgcn_mfma_f32_16x16x32_bf16(ah[jt], bl[it], acc[jt][it], 0, 0, 0);
                acc[jt][it] = __builtin_amdgcn_mfma_f32_16x16x32_bf16(al[jt], bh[it], acc[jt][it], 0, 0, 0);
            }
        __syncthreads();
    }

    // Epilogue: e = exp(scale*s); store E[i][j] split-bf16; partial-D reduce.
    const float scale = 0.02209708691207961f;  // 1/sqrt(2048)
    ushort* ehb = eh + (size_t)b * Nn * Nn;
    ushort* elb = el + (size_t)b * Nn * Nn;
    float* dpb  = dpart + (size_t)b * Nn;

    float esum[4][4];
    #pragma unroll
    for (int jt = 0; jt < 4; ++jt)
        #pragma unroll
        for (int rg = 0; rg < 4; ++rg) esum[jt][rg] = 0.f;

    #pragma unroll
    for (int jt = 0; jt < 4; ++jt) {
        const int jb = j0 + wy * 64 + jt * 16 + lg * 4;   // D-row (A=k side)
        #pragma unroll
        for (int it = 0; it < 4; ++it) {
            const int i = i0 + wx * 64 + it * 16 + lrow;  // D-col (B=q side)
            ushort4 h4, l4;
            #pragma unroll
            for (int rg = 0; rg < 4; ++rg) {
                float e = __expf(acc[jt][it][rg] * scale);
                esum[jt][rg] += e;
                ushort hh = bf16_rne(e);
                (&h4.x)[rg] = hh;
                (&l4.x)[rg] = bf16_rne(e - bf16_to_f32(hh));
            }
            *(ushort4*)(ehb + (size_t)i * Nn + jb) = h4;
            *(ushort4*)(elb + (size_t)i * Nn + jb) = l4;
        }
    }
    // reduce esum over the 16 i-lanes (lr), leaders atomicAdd into Dp[j]
    #pragma unroll
    for (int jt = 0; jt < 4; ++jt)
        #pragma unroll
        for (int rg = 0; rg < 4; ++rg) {
            float v = esum[jt][rg];
            v += __shfl_xor(v, 1);
            v += __shfl_xor(v, 2);
            v += __shfl_xor(v, 4);
            v += __shfl_xor(v, 8);
            if (lrow == 0)
                atomicAdd(dpb + j0 + wy * 64 + jt * 16 + lg * 4 + rg, v);
        }
}

// ---------------------------------------------------------------------------
// Kernel 2.5: vT split-transpose WITH 1/D fold.
// v'[b][w][j] = split-bf16( v32[b][j][w] / D[j] ).
// ---------------------------------------------------------------------------
__global__ __launch_bounds__(256) void vt_kernel(
    const float* __restrict__ v32, const float* __restrict__ dpart,
    ushort* __restrict__ vthi, ushort* __restrict__ vtlo)
{
    __shared__ ushort Thi[64*66], Tlo[64*66];
    const int tid = threadIdx.x;
    const int j0 = blockIdx.x * 64;
    const int w0 = blockIdx.y * 64;
    const int b  = blockIdx.z;
    const float* vb = v32 + (size_t)b * Nn * Ww;
    const float* dpb = dpart + (size_t)b * Nn;

    #pragma unroll
    for (int r = 0; r < 4; ++r) {
        int j  = (tid >> 4) + r * 16;
        int wl = (tid & 15) * 4;
        float invd = 1.0f / dpb[j0 + j];
        float4 tv = *(const float4*)(vb + (size_t)(j0 + j) * Ww + w0 + wl);
        float f[4] = {tv.x * invd, tv.y * invd, tv.z * invd, tv.w * invd};
        #pragma unroll
        for (int c = 0; c < 4; ++c) {
            ushort h = bf16_rne(f[c]);
            Thi[(wl + c) * 66 + j] = h;
            Tlo[(wl + c) * 66 + j] = bf16_rne(f[c] - bf16_to_f32(h));
        }
    }
    __syncthreads();
    {
        int wl = tid >> 2, jc = (tid & 3) * 16;
        size_t go = ((size_t)b * Ww + w0 + wl) * Nn + j0 + jc;
        uint tH[8], tL[8];
        #pragma unroll
        for (int u = 0; u < 8; ++u) {
            tH[u] = *(const uint*)&Thi[wl * 66 + jc + u * 2];
            tL[u] = *(const uint*)&Tlo[wl * 66 + jc + u * 2];
        }
        #pragma unroll
        for (int u = 0; u < 2; ++u) {
            uint4 hh; hh.x = tH[u*4+0]; hh.y = tH[u*4+1]; hh.z = tH[u*4+2]; hh.w = tH[u*4+3];
            uint4 ll; ll.x = tL[u*4+0]; ll.y = tL[u*4+1]; ll.z = tL[u*4+2]; ll.w = tL[u*4+3];
            *(uint4*)(vthi + go + u * 8) = hh;
            *(uint4*)(vtlo + go + u * 8) = ll;
        }
    }
}

// ---------------------------------------------------------------------------
// Kernel 3: PV via split-bf16 MFMA. out[b,i,w] += sum_j E[i][j] * v'[j][w].
// Both LDS sides are DIRECT bf16x8 row copies (no transpose scatter):
//   A = E[i][j] (i-major, j contiguous), B = v'T[w][j] (w-major).
// LDS rows stride 40 ushorts (80 B): bank pattern period 8, all distinct ->
// 2-way max on b128 ops = free (m136). T14 issue-early prefetch. ksplit=2.
// Block 128i x 128w, BK=32, 4 waves (2x2), wave tile 64x64.
// grid (16 i, 2 wt x 2 kz, 8 b) = 512 blocks.
// ---------------------------------------------------------------------------
__global__ __launch_bounds__(256) void pv_mfma_kernel(
    const ushort* __restrict__ eh, const ushort* __restrict__ el,
    const ushort* __restrict__ vthi, const ushort* __restrict__ vtlo,
    float* __restrict__ out)
{
    __shared__ alignas(16) ushort Ah[128*40], Al[128*40];
    __shared__ alignas(16) ushort Bh[128*40], Bl[128*40];   // 40 KB total

    const int tid = threadIdx.x;
    const int i0 = blockIdx.x * 128;
    const int wt = blockIdx.y & 1, kz = blockIdx.y >> 1;
    const int w0 = wt * 128;
    const int b  = blockIdx.z;

    const ushort* ehb = eh + (size_t)b * Nn * Nn;
    const ushort* elb = el + (size_t)b * Nn * Nn;
    const ushort* vhb = vthi + (size_t)b * Ww * Nn;
    const ushort* vlb = vtlo + (size_t)b * Ww * Nn;

    const int wave = tid >> 6, lane = tid & 63;
    const int wy = wave >> 1, wx = wave & 1;    // i-half / w-half
    const int lr = lane & 15, lg = lane >> 4;

    f32x4 acc[4][4];
    #pragma unroll
    for (int a = 0; a < 4; ++a)
        #pragma unroll
        for (int c = 0; c < 4; ++c) acc[a][c] = (f32x4){0.f, 0.f, 0.f, 0.f};

    // staging assignment: thread t handles row (t>>1), 16-j half (t&1)
    const int srow = tid >> 1;
    const int sjc  = (tid & 1) * 16;
    const size_t aoff0 = (size_t)(i0 + srow) * Nn + (size_t)kz * 1024 + sjc;
    const size_t boff0 = (size_t)(w0 + srow) * Nn + (size_t)kz * 1024 + sjc;
    const int lbase = srow * 40 + sjc;

    // prologue: prefetch tile 0
    bf16x8 rah0 = *(const bf16x8*)(ehb + aoff0);
    bf16x8 rah1 = *(const bf16x8*)(ehb + aoff0 + 8);
    bf16x8 ral0 = *(const bf16x8*)(elb + aoff0);
    bf16x8 ral1 = *(const bf16x8*)(elb + aoff0 + 8);
    bf16x8 rbh0 = *(const bf16x8*)(vhb + boff0);
    bf16x8 rbh1 = *(const bf16x8*)(vhb + boff0 + 8);
    bf16x8 rbl0 = *(const bf16x8*)(vlb + boff0);
    bf16x8 rbl1 = *(const bf16x8*)(vlb + boff0 + 8);

    for (int ks = 0; ks < 32; ++ks) {
        // write staged regs -> LDS (direct rows, stride 40)
        *(bf16x8*)&Ah[lbase]     = rah0;
        *(bf16x8*)&Ah[lbase + 8] = rah1;
        *(bf16x8*)&Al[lbase]     = ral0;
        *(bf16x8*)&Al[lbase + 8] = ral1;
        *(bf16x8*)&Bh[lbase]     = rbh0;
        *(bf16x8*)&Bh[lbase + 8] = rbh1;
        *(bf16x8*)&Bl[lbase]     = rbl0;
        *(bf16x8*)&Bl[lbase + 8] = rbl1;
        __syncthreads();

        // T14: issue next-tile loads now; latency hides under frag reads+MFMA
        if (ks < 31) {
            const size_t ao = aoff0 + (ks + 1) * 32;
            const size_t bo = boff0 + (ks + 1) * 32;
            rah0 = *(const bf16x8*)(ehb + ao);
            rah1 = *(const bf16x8*)(ehb + ao + 8);
            ral0 = *(const bf16x8*)(elb + ao);
            ral1 = *(const bf16x8*)(elb + ao + 8);
            rbh0 = *(const bf16x8*)(vhb + bo);
            rbh1 = *(const bf16x8*)(vhb + bo + 8);
            rbl0 = *(const bf16x8*)(vlb + bo);
            rbl1 = *(const bf16x8*)(vlb + bo + 8);
        }

        bf16x8 afh[4], afl[4], bfh[4], bfl[4];
        #pragma unroll
        for (int t = 0; t < 4; ++t) {
            const int ar = (wy * 64 + t * 16 + lr) * 40 + lg * 8;
            afh[t] = *(const bf16x8*)&Ah[ar];
            afl[t] = *(const bf16x8*)&Al[ar];
            const int br = (wx * 64 + t * 16 + lr) * 40 + lg * 8;
            bfh[t] = *(const bf16x8*)&Bh[br];
            bfl[t] = *(const bf16x8*)&Bl[br];
        }
        #pragma unroll
        for (int ia = 0; ia < 4; ++ia)
            #pragma unroll
            for (int ib = 0; ib < 4; ++ib) {
                acc[ia][ib] = __builtin_amdgcn_mfma_f32_16x16x32_bf16(afh[ia], bfh[ib], acc[ia][ib], 0, 0, 0);
                acc[ia][ib] = __builtin_amdgcn_mfma_f32_16x16x32_bf16(afh[ia], bfl[ib], acc[ia][ib], 0, 0, 0);
                acc[ia][ib] = __builtin_amdgcn_mfma_f32_16x16x32_bf16(afl[ia], bfh[ib], acc[ia][ib], 0, 0, 0);
            }
        __syncthreads();
    }

    // epilogue: accumulate partials (ksplit 2) into pre-zeroed out
    #pragma unroll
    for (int ia = 0; ia < 4; ++ia) {
        const int ibase = i0 + wy * 64 + ia * 16 + lg * 4;
        #pragma unroll
        for (int ib = 0; ib < 4; ++ib) {
            const int w = w0 + wx * 64 + ib * 16 + lr;
            #pragma unroll
            for (int rg = 0; rg < 4; ++rg) {
                size_t gidx = ((size_t)(b * Nn + ibase + rg)) * Ww + w;
                atomicAdd(out + gidx, acc[ia][ib][rg]);
            }
        }
    }
}

// ---------------------------------------------------------------------------
// Kernel 4: out += q (reconstructed from split bf16). grid 4096, block 256.
// ---------------------------------------------------------------------------
__global__ __launch_bounds__(256) void qadd_kernel(
    const ushort* __restrict__ qhi, const ushort* __restrict__ qlo,
    float* __restrict__ out)
{
    const size_t g4 = ((size_t)blockIdx.x * 256 + threadIdx.x) * 4;
    ushort4 h = *(const ushort4*)(qhi + g4);
    ushort4 l = *(const ushort4*)(qlo + g4);
    float4 o = *(const float4*)(out + g4);
    o.x += bf16_to_f32(h.x) + bf16_to_f32(l.x);
    o.y += bf16_to_f32(h.y) + bf16_to_f32(l.y);
    o.z += bf16_to_f32(h.z) + bf16_to_f32(l.z);
    o.w += bf16_to_f32(h.w) + bf16_to_f32(l.w);
    *(float4*)(out + g4) = o;
}

// ---------------------------------------------------------------------------
// Launch. ws: v32 f32 [16MB] | qhi,qlo,khi,klo bf16 [4x8MB] | Eh [64MB] |
// El [64MB] | Dp f32 [64KB] = 176.06 MiB. vthi/vtlo reuse khi/klo after
// scores consumed k.
// ---------------------------------------------------------------------------
extern "C" void kernel_launch(void* const* d_in, const int* in_sizes, int n_in,
                              void* d_out, int out_size, void* d_ws, size_t ws_size,
                              hipStream_t stream) {
    const float* x  = (const float*)d_in[0];
    const float* Wq = (const float*)d_in[1];
    const float* bq = (const float*)d_in[2];
    const float* Wk = (const float*)d_in[3];
    const float* bk = (const float*)d_in[4];
    const float* Wv = (const float*)d_in[5];
    const float* bv = (const float*)d_in[6];
    // d_in[7] = valid_len (unused by the reference forward)
    float* out = (float*)d_out;

    float*  v32 = (float*)d_ws;
    ushort* qhi = (ushort*)(v32 + (size_t)Mtot * Ww);
    ushort* qlo = qhi + (size_t)Mtot * Ww;
    ushort* khi = qlo + (size_t)Mtot * Ww;
    ushort* klo = khi + (size_t)Mtot * Ww;
    ushort* eh  = klo + (size_t)Mtot * Ww;
    ushort* el  = eh + (size_t)Bb * Nn * Nn;
    float*  dpart = (float*)(el + (size_t)Bb * Nn * Nn);
    ushort* vthi = khi;   // reuse after scores_mfma consumed k
    ushort* vtlo = klo;

    hipMemsetAsync(out, 0, (size_t)out_size * sizeof(float), stream);
    hipMemsetAsync(dpart, 0, (size_t)Bb * Nn * sizeof(float), stream);
    qkv_proj_kernel<<<dim3(128, 12), 256, 0, stream>>>(x, Wq, bq, Wk, bk, Wv, bv,
                                                       v32, qhi, qlo, khi, klo);
    scores_mfma_kernel<<<dim3(16, 16, 8), 256, 0, stream>>>(qhi, qlo, khi, klo, eh, el, dpart);
    vt_kernel<<<dim3(32, 4, 8), 256, 0, stream>>>(v32, dpart, vthi, vtlo);
    pv_mfma_kernel<<<dim3(16, 4, 8), 256, 0, stream>>>(eh, el, vthi, vtlo, out);
    qadd_kernel<<<dim3(4096), 256, 0, stream>>>(qhi, qlo, out);
}

// Round 8
// 325.905 us; speedup vs baseline: 1.1693x; 1.0606x over previous
//
#include <hip/hip_runtime.h>
#include <math.h>

// Problem constants (reference: B=8, N=2048, C=256, W=256)
#define Bb 8
#define Nn 2048
#define Cc 256
#define Ww 256
#define Mtot (Bb*Nn)   // 16384

typedef __attribute__((ext_vector_type(8))) short bf16x8;
typedef __attribute__((ext_vector_type(4))) float f32x4;

__device__ __forceinline__ ushort bf16_rne(float f) {
    uint u = __float_as_uint(f);
    return (ushort)((u + 0x7FFFu + ((u >> 16) & 1u)) >> 16);
}
__device__ __forceinline__ float bf16_to_f32(ushort h) {
    return __uint_as_float(((uint)h) << 16);
}

// ---------------------------------------------------------------------------
// Kernel 1: fused QKV projection. r = relu(x·Wᵀ + b). (unchanged, proven)
// ---------------------------------------------------------------------------
__global__ __launch_bounds__(256) void qkv_proj_kernel(
    const float* __restrict__ x,
    const float* __restrict__ Wq, const float* __restrict__ bq,
    const float* __restrict__ Wk, const float* __restrict__ bk,
    const float* __restrict__ Wv, const float* __restrict__ bv,
    float* __restrict__ v32,
    ushort* __restrict__ qhi, ushort* __restrict__ qlo,
    ushort* __restrict__ khi, ushort* __restrict__ klo)
{
    __shared__ float xs[16][132];
    __shared__ float ws[16][68];

    const int tid = threadIdx.x;
    const int tn = tid & 15;
    const int tm = tid >> 4;
    const int m0 = blockIdx.x * 128;
    const int nt = blockIdx.y;
    const int which = nt >> 2;
    const int w0 = (nt & 3) * 64;

    const float* Wm = (which == 0) ? Wq : ((which == 1) ? Wk : Wv);
    const float* bm = (which == 0) ? bq : ((which == 1) ? bk : bv);

    float acc[8][4];
    #pragma unroll
    for (int i = 0; i < 8; ++i)
        #pragma unroll
        for (int j = 0; j < 4; ++j) acc[i][j] = 0.f;

    for (int kc = 0; kc < Cc; kc += 16) {
        #pragma unroll
        for (int l = 0; l < 2; ++l) {
            int s = tid + l * 256;
            int r = s >> 2, c4 = s & 3;
            float4 tv = *(const float4*)(x + (size_t)(m0 + r) * Cc + kc + c4 * 4);
            xs[c4*4+0][r] = tv.x; xs[c4*4+1][r] = tv.y;
            xs[c4*4+2][r] = tv.z; xs[c4*4+3][r] = tv.w;
        }
        {
            int r = tid >> 2, c4 = tid & 3;
            float4 tv = *(const float4*)(Wm + (size_t)(w0 + r) * Cc + kc + c4 * 4);
            ws[c4*4+0][r] = tv.x; ws[c4*4+1][r] = tv.y;
            ws[c4*4+2][r] = tv.z; ws[c4*4+3][r] = tv.w;
        }
        __syncthreads();
        #pragma unroll
        for (int kk = 0; kk < 16; ++kk) {
            float4 a0 = *(const float4*)&xs[kk][tm*4];
            float4 a1 = *(const float4*)&xs[kk][tm*4 + 64];
            float4 b0 = *(const float4*)&ws[kk][tn*4];
            float a[8] = {a0.x,a0.y,a0.z,a0.w,a1.x,a1.y,a1.z,a1.w};
            float b[4] = {b0.x,b0.y,b0.z,b0.w};
            #pragma unroll
            for (int i = 0; i < 8; ++i)
                #pragma unroll
                for (int j = 0; j < 4; ++j) acc[i][j] += a[i] * b[j];
        }
        __syncthreads();
    }

    float4 bias = *(const float4*)(bm + w0 + tn*4);
    #pragma unroll
    for (int i = 0; i < 8; ++i) {
        int m = m0 + tm*4 + (i & 3) + (i >> 2) * 64;
        float rr0 = fmaxf(acc[i][0] + bias.x, 0.f);
        float rr1 = fmaxf(acc[i][1] + bias.y, 0.f);
        float rr2 = fmaxf(acc[i][2] + bias.z, 0.f);
        float rr3 = fmaxf(acc[i][3] + bias.w, 0.f);
        size_t o = (size_t)m * Ww + w0 + tn*4;
        if (which == 2) {
            float4 r; r.x = rr0; r.y = rr1; r.z = rr2; r.w = rr3;
            *(float4*)(v32 + o) = r;
        } else {
            ushort4 h, l;
            h.x = bf16_rne(rr0); l.x = bf16_rne(rr0 - bf16_to_f32(h.x));
            h.y = bf16_rne(rr1); l.y = bf16_rne(rr1 - bf16_to_f32(h.y));
            h.z = bf16_rne(rr2); l.z = bf16_rne(rr2 - bf16_to_f32(h.z));
            h.w = bf16_rne(rr3); l.w = bf16_rne(rr3 - bf16_to_f32(h.w));
            ushort* hp = (which == 0) ? qhi : khi;
            ushort* lp = (which == 0) ? qlo : klo;
            *(ushort4*)(hp + o) = h;
            *(ushort4*)(lp + o) = l;
        }
    }
}

// ---------------------------------------------------------------------------
// Kernel 2: E[b][i][j] = bf16( exp(scale * sum_w k[b,j,w]*q[b,i,w]) )  (PLAIN
// bf16 now) + D[j] = sum_i e_ROUNDED (atomicAdd into pre-zeroed Dp).
// D computed from the ROUNDED e values PV will actually sum -> attn is an
// exact probability distribution over PV's inputs (errors self-normalize).
// No max-subtraction: |s·scale| <~ 14, exp <= 1.2e6, fp32-safe; softmax max
// cancels exactly; 1/D folded into v' (vt_kernel).
// ---------------------------------------------------------------------------
__global__ __launch_bounds__(256) void scores_mfma_kernel(
    const ushort* __restrict__ qhi, const ushort* __restrict__ qlo,
    const ushort* __restrict__ khi, const ushort* __restrict__ klo,
    ushort* __restrict__ eh, float* __restrict__ dpart)
{
    __shared__ ushort lkh[4096], lkl[4096], lqh[4096], lql[4096];

    const int tid = threadIdx.x;
    const int i0 = blockIdx.x * 128;
    const int j0 = blockIdx.y * 128;
    const int b  = blockIdx.z;

    const ushort* kh = khi + ((size_t)b * Nn + j0) * Ww;
    const ushort* kl = klo + ((size_t)b * Nn + j0) * Ww;
    const ushort* qh = qhi + ((size_t)b * Nn + i0) * Ww;
    const ushort* ql = qlo + ((size_t)b * Nn + i0) * Ww;

    const int wave = tid >> 6, lane = tid & 63;
    const int wy = wave >> 1, wx = wave & 1;
    const int lrow = lane & 15, lg = lane >> 4;

    f32x4 acc[4][4];
    #pragma unroll
    for (int a = 0; a < 4; ++a)
        #pragma unroll
        for (int c = 0; c < 4; ++c) acc[a][c] = (f32x4){0.f, 0.f, 0.f, 0.f};

    const int cg = tid & 3;
    const int cr0 = tid >> 2;

    for (int kc = 0; kc < Ww; kc += 32) {
        #pragma unroll
        for (int h = 0; h < 2; ++h) {
            int r = cr0 + h * 64;
            int gg = cg ^ ((r >> 1) & 3);
            int li = r * 32 + gg * 8;
            size_t go = (size_t)r * Ww + kc + cg * 8;
            *(bf16x8*)&lkh[li] = *(const bf16x8*)(kh + go);
            *(bf16x8*)&lkl[li] = *(const bf16x8*)(kl + go);
            *(bf16x8*)&lqh[li] = *(const bf16x8*)(qh + go);
            *(bf16x8*)&lql[li] = *(const bf16x8*)(ql + go);
        }
        __syncthreads();

        bf16x8 ah[4], al[4], bh[4], bl[4];
        #pragma unroll
        for (int t = 0; t < 4; ++t) {
            int ra = wy * 64 + t * 16 + lrow;
            int ia = ra * 32 + ((lg ^ ((ra >> 1) & 3)) * 8);
            ah[t] = *(const bf16x8*)&lkh[ia];
            al[t] = *(const bf16x8*)&lkl[ia];
            int rb = wx * 64 + t * 16 + lrow;
            int ib = rb * 32 + ((lg ^ ((rb >> 1) & 3)) * 8);
            bh[t] = *(const bf16x8*)&lqh[ib];
            bl[t] = *(const bf16x8*)&lql[ib];
        }
        #pragma unroll
        for (int jt = 0; jt < 4; ++jt)
            #pragma unroll
            for (int it = 0; it < 4; ++it) {
                acc[jt][it] = __builtin_amdgcn_mfma_f32_16x16x32_bf16(ah[jt], bh[it], acc[jt][it], 0, 0, 0);
                acc[jt][it] = __builtin_amdgcn_mfma_f32_16x16x32_bf16(ah[jt], bl[it], acc[jt][it], 0, 0, 0);
                acc[jt][it] = __builtin_amdgcn_mfma_f32_16x16x32_bf16(al[jt], bh[it], acc[jt][it], 0, 0, 0);
            }
        __syncthreads();
    }

    // Epilogue: e = exp(scale*s); store E[i][j] plain bf16; D from rounded e.
    const float scale = 0.02209708691207961f;  // 1/sqrt(2048)
    ushort* ehb = eh + (size_t)b * Nn * Nn;
    float* dpb  = dpart + (size_t)b * Nn;

    float esum[4][4];
    #pragma unroll
    for (int jt = 0; jt < 4; ++jt)
        #pragma unroll
        for (int rg = 0; rg < 4; ++rg) esum[jt][rg] = 0.f;

    #pragma unroll
    for (int jt = 0; jt < 4; ++jt) {
        const int jb = j0 + wy * 64 + jt * 16 + lg * 4;   // D-row (A=k side)
        #pragma unroll
        for (int it = 0; it < 4; ++it) {
            const int i = i0 + wx * 64 + it * 16 + lrow;  // D-col (B=q side)
            ushort4 h4;
            #pragma unroll
            for (int rg = 0; rg < 4; ++rg) {
                float e = __expf(acc[jt][it][rg] * scale);
                ushort hh = bf16_rne(e);
                (&h4.x)[rg] = hh;
                esum[jt][rg] += bf16_to_f32(hh);
            }
            *(ushort4*)(ehb + (size_t)i * Nn + jb) = h4;
        }
    }
    // reduce esum over the 16 i-lanes (lrow), leaders atomicAdd into Dp[j]
    #pragma unroll
    for (int jt = 0; jt < 4; ++jt)
        #pragma unroll
        for (int rg = 0; rg < 4; ++rg) {
            float v = esum[jt][rg];
            v += __shfl_xor(v, 1);
            v += __shfl_xor(v, 2);
            v += __shfl_xor(v, 4);
            v += __shfl_xor(v, 8);
            if (lrow == 0)
                atomicAdd(dpb + j0 + wy * 64 + jt * 16 + lg * 4 + rg, v);
        }
}

// ---------------------------------------------------------------------------
// Kernel 2.5: vT split-transpose WITH 1/D fold. (unchanged, proven)
// v'[b][w][j] = split-bf16( v32[b][j][w] / D[j] ).
// ---------------------------------------------------------------------------
__global__ __launch_bounds__(256) void vt_kernel(
    const float* __restrict__ v32, const float* __restrict__ dpart,
    ushort* __restrict__ vthi, ushort* __restrict__ vtlo)
{
    __shared__ ushort Thi[64*66], Tlo[64*66];
    const int tid = threadIdx.x;
    const int j0 = blockIdx.x * 64;
    const int w0 = blockIdx.y * 64;
    const int b  = blockIdx.z;
    const float* vb = v32 + (size_t)b * Nn * Ww;
    const float* dpb = dpart + (size_t)b * Nn;

    #pragma unroll
    for (int r = 0; r < 4; ++r) {
        int j  = (tid >> 4) + r * 16;
        int wl = (tid & 15) * 4;
        float invd = 1.0f / dpb[j0 + j];
        float4 tv = *(const float4*)(vb + (size_t)(j0 + j) * Ww + w0 + wl);
        float f[4] = {tv.x * invd, tv.y * invd, tv.z * invd, tv.w * invd};
        #pragma unroll
        for (int c = 0; c < 4; ++c) {
            ushort h = bf16_rne(f[c]);
            Thi[(wl + c) * 66 + j] = h;
            Tlo[(wl + c) * 66 + j] = bf16_rne(f[c] - bf16_to_f32(h));
        }
    }
    __syncthreads();
    {
        int wl = tid >> 2, jc = (tid & 3) * 16;
        size_t go = ((size_t)b * Ww + w0 + wl) * Nn + j0 + jc;
        uint tH[8], tL[8];
        #pragma unroll
        for (int u = 0; u < 8; ++u) {
            tH[u] = *(const uint*)&Thi[wl * 66 + jc + u * 2];
            tL[u] = *(const uint*)&Tlo[wl * 66 + jc + u * 2];
        }
        #pragma unroll
        for (int u = 0; u < 2; ++u) {
            uint4 hh; hh.x = tH[u*4+0]; hh.y = tH[u*4+1]; hh.z = tH[u*4+2]; hh.w = tH[u*4+3];
            uint4 ll; ll.x = tL[u*4+0]; ll.y = tL[u*4+1]; ll.z = tL[u*4+2]; ll.w = tL[u*4+3];
            *(uint4*)(vthi + go + u * 8) = hh;
            *(uint4*)(vtlo + go + u * 8) = ll;
        }
    }
}

// ---------------------------------------------------------------------------
// Kernel 3: PV. part[kz][b,i,w] = sum_{j in kz-half} E[i][j] * v'[j][w].
// A = plain-bf16 E (i-major), B = split v'T (w-major): 2-pass MFMA.
// Tile 128i x 64w, BK=32, ksplit 2 -> DIRECT stores to two partial buffers
// (no atomics, no out-memset). 4 waves (2i x 2w), wave tile 64i x 32w.
// Stride-40 LDS rows (proven conflict-0 in r7) + T14 issue-early prefetch.
// grid (16 i, 4 wt x 2 kz, 8 b) = 1024 blocks = 4 blocks/CU.
// ---------------------------------------------------------------------------
__global__ __launch_bounds__(256) void pv_mfma_kernel(
    const ushort* __restrict__ eh,
    const ushort* __restrict__ vthi, const ushort* __restrict__ vtlo,
    float* __restrict__ part)
{
    __shared__ alignas(16) ushort Ah[128*40];            // E tile  [i][j]
    __shared__ alignas(16) ushort Bh[64*40], Bl[64*40];  // v' tile [w][j]

    const int tid = threadIdx.x;
    const int i0 = blockIdx.x * 128;
    const int wt = blockIdx.y & 3, kz = blockIdx.y >> 2;
    const int w0 = wt * 64;
    const int b  = blockIdx.z;

    const ushort* ehb = eh + (size_t)b * Nn * Nn;
    const ushort* vhb = vthi + (size_t)b * Ww * Nn;
    const ushort* vlb = vtlo + (size_t)b * Ww * Nn;

    const int wave = tid >> 6, lane = tid & 63;
    const int wy = wave >> 1, wx = wave & 1;    // i-half(64) / w-half(32)
    const int lr = lane & 15, lg = lane >> 4;

    f32x4 acc[4][2];
    #pragma unroll
    for (int a = 0; a < 4; ++a)
        #pragma unroll
        for (int c = 0; c < 2; ++c) acc[a][c] = (f32x4){0.f, 0.f, 0.f, 0.f};

    // staging: threads 0-127 -> A row tid (64B = full 32-j span);
    //          threads 128-255 -> s=tid-128: arr s>>6 (h/l), row s&63.
    const bool isA = tid < 128;
    const int srow = isA ? tid : (tid & 63);
    const ushort* gsrc = isA ? ehb : ((tid & 64) ? vlb : vhb);
    const size_t goff0 = isA
        ? ((size_t)(i0 + srow) * Nn + (size_t)kz * 1024)
        : ((size_t)(w0 + srow) * Nn + (size_t)kz * 1024);
    ushort* ldst = isA ? &Ah[srow * 40] : ((tid & 64) ? &Bl[srow * 40] : &Bh[srow * 40]);

    // prologue: prefetch tile 0 (4 x bf16x8 = 64B per thread)
    bf16x8 r0 = *(const bf16x8*)(gsrc + goff0);
    bf16x8 r1 = *(const bf16x8*)(gsrc + goff0 + 8);
    bf16x8 r2 = *(const bf16x8*)(gsrc + goff0 + 16);
    bf16x8 r3 = *(const bf16x8*)(gsrc + goff0 + 24);

    for (int ks = 0; ks < 32; ++ks) {
        *(bf16x8*)(ldst)      = r0;
        *(bf16x8*)(ldst + 8)  = r1;
        *(bf16x8*)(ldst + 16) = r2;
        *(bf16x8*)(ldst + 24) = r3;
        __syncthreads();

        // T14: issue next-tile loads; latency hides under frag reads + MFMA
        if (ks < 31) {
            const size_t go = goff0 + (ks + 1) * 32;
            r0 = *(const bf16x8*)(gsrc + go);
            r1 = *(const bf16x8*)(gsrc + go + 8);
            r2 = *(const bf16x8*)(gsrc + go + 16);
            r3 = *(const bf16x8*)(gsrc + go + 24);
        }

        bf16x8 af[4], bfh[2], bfl[2];
        #pragma unroll
        for (int t = 0; t < 4; ++t)
            af[t] = *(const bf16x8*)&Ah[(wy * 64 + t * 16 + lr) * 40 + lg * 8];
        #pragma unroll
        for (int t = 0; t < 2; ++t) {
            const int br = (wx * 32 + t * 16 + lr) * 40 + lg * 8;
            bfh[t] = *(const bf16x8*)&Bh[br];
            bfl[t] = *(const bf16x8*)&Bl[br];
        }
        #pragma unroll
        for (int ia = 0; ia < 4; ++ia)
            #pragma unroll
            for (int ib = 0; ib < 2; ++ib) {
                acc[ia][ib] = __builtin_amdgcn_mfma_f32_16x16x32_bf16(af[ia], bfh[ib], acc[ia][ib], 0, 0, 0);
                acc[ia][ib] = __builtin_amdgcn_mfma_f32_16x16x32_bf16(af[ia], bfl[ib], acc[ia][ib], 0, 0, 0);
            }
        __syncthreads();
    }

    // epilogue: direct stores into this kz's partial buffer (64B lines via lr)
    float* pout = part + (size_t)kz * Mtot * Ww;
    #pragma unroll
    for (int ia = 0; ia < 4; ++ia) {
        const int ibase = i0 + wy * 64 + ia * 16 + lg * 4;
        #pragma unroll
        for (int ib = 0; ib < 2; ++ib) {
            const int w = w0 + wx * 32 + ib * 16 + lr;
            #pragma unroll
            for (int rg = 0; rg < 4; ++rg)
                pout[((size_t)(b * Nn + ibase + rg)) * Ww + w] = acc[ia][ib][rg];
        }
    }
}

// ---------------------------------------------------------------------------
// Kernel 4: out = part0 + part1 + q (q from split bf16). grid 4096, blk 256.
// ---------------------------------------------------------------------------
__global__ __launch_bounds__(256) void qadd_kernel(
    const float* __restrict__ part,
    const ushort* __restrict__ qhi, const ushort* __restrict__ qlo,
    float* __restrict__ out)
{
    const size_t g4 = ((size_t)blockIdx.x * 256 + threadIdx.x) * 4;
    float4 p0 = *(const float4*)(part + g4);
    float4 p1 = *(const float4*)(part + (size_t)Mtot * Ww + g4);
    ushort4 h = *(const ushort4*)(qhi + g4);
    ushort4 l = *(const ushort4*)(qlo + g4);
    float4 o;
    o.x = p0.x + p1.x + bf16_to_f32(h.x) + bf16_to_f32(l.x);
    o.y = p0.y + p1.y + bf16_to_f32(h.y) + bf16_to_f32(l.y);
    o.z = p0.z + p1.z + bf16_to_f32(h.z) + bf16_to_f32(l.z);
    o.w = p0.w + p1.w + bf16_to_f32(h.w) + bf16_to_f32(l.w);
    *(float4*)(out + g4) = o;
}

// ---------------------------------------------------------------------------
// Launch. ws: v32 f32 [16MB] | qhi,qlo,khi,klo bf16 [4x8MB] | Eh bf16 [64MB]
// | part f32 [2x16MB] | Dp f32 [64KB] = 144.06 MiB.
// vthi/vtlo reuse khi/klo after scores consumed k.
// ---------------------------------------------------------------------------
extern "C" void kernel_launch(void* const* d_in, const int* in_sizes, int n_in,
                              void* d_out, int out_size, void* d_ws, size_t ws_size,
                              hipStream_t stream) {
    const float* x  = (const float*)d_in[0];
    const float* Wq = (const float*)d_in[1];
    const float* bq = (const float*)d_in[2];
    const float* Wk = (const float*)d_in[3];
    const float* bk = (const float*)d_in[4];
    const float* Wv = (const float*)d_in[5];
    const float* bv = (const float*)d_in[6];
    // d_in[7] = valid_len (unused by the reference forward)
    float* out = (float*)d_out;

    float*  v32 = (float*)d_ws;
    ushort* qhi = (ushort*)(v32 + (size_t)Mtot * Ww);
    ushort* qlo = qhi + (size_t)Mtot * Ww;
    ushort* khi = qlo + (size_t)Mtot * Ww;
    ushort* klo = khi + (size_t)Mtot * Ww;
    ushort* eh  = klo + (size_t)Mtot * Ww;
    float*  part = (float*)(eh + (size_t)Bb * Nn * Nn);
    float*  dpart = part + (size_t)2 * Mtot * Ww;
    ushort* vthi = khi;   // reuse after scores_mfma consumed k
    ushort* vtlo = klo;

    hipMemsetAsync(dpart, 0, (size_t)Bb * Nn * sizeof(float), stream);
    qkv_proj_kernel<<<dim3(128, 12), 256, 0, stream>>>(x, Wq, bq, Wk, bk, Wv, bv,
                                                       v32, qhi, qlo, khi, klo);
    scores_mfma_kernel<<<dim3(16, 16, 8), 256, 0, stream>>>(qhi, qlo, khi, klo, eh, dpart);
    vt_kernel<<<dim3(32, 4, 8), 256, 0, stream>>>(v32, dpart, vthi, vtlo);
    pv_mfma_kernel<<<dim3(16, 8, 8), 256, 0, stream>>>(eh, vthi, vtlo, part);
    qadd_kernel<<<dim3(4096), 256, 0, stream>>>(part, qhi, qlo, out);
}

// Round 10
// 286.348 us; speedup vs baseline: 1.3309x; 1.1381x over previous
//
#include <hip/hip_runtime.h>
#include <math.h>

// Problem constants (reference: B=8, N=2048, C=256, W=256)
#define Bb 8
#define Nn 2048
#define Cc 256
#define Ww 256
#define Mtot (Bb*Nn)   // 16384

typedef __attribute__((ext_vector_type(8))) short bf16x8;
typedef __attribute__((ext_vector_type(4))) float f32x4;

__device__ __forceinline__ ushort bf16_rne(float f) {
    uint u = __float_as_uint(f);
    return (ushort)((u + 0x7FFFu + ((u >> 16) & 1u)) >> 16);
}
__device__ __forceinline__ float bf16_to_f32(ushort h) {
    return __uint_as_float(((uint)h) << 16);
}

// ---------------------------------------------------------------------------
// Kernel 0: split x and Wq/Wk/Wv into bf16 hi/lo for the MFMA QKV.
// blocks 0..4095: x (4 elems/thread). blocks 4096..4287: the three W mats.
// ---------------------------------------------------------------------------
__global__ __launch_bounds__(256) void prep_kernel(
    const float* __restrict__ x,
    const float* __restrict__ Wq, const float* __restrict__ Wk,
    const float* __restrict__ Wv,
    ushort* __restrict__ xh, ushort* __restrict__ xl,
    ushort* __restrict__ wqh, ushort* __restrict__ wql,
    ushort* __restrict__ wkh, ushort* __restrict__ wkl,
    ushort* __restrict__ wvh, ushort* __restrict__ wvl)
{
    const int tid = threadIdx.x;
    const float* src;
    ushort *dh, *dl;
    size_t off;
    if (blockIdx.x < 4096) {
        off = ((size_t)blockIdx.x * 256 + tid) * 4;
        src = x; dh = xh; dl = xl;
    } else {
        size_t s = ((size_t)(blockIdx.x - 4096) * 256 + tid) * 4;
        int which = (int)(s >> 16);
        off = s & 65535u;
        src = (which == 0) ? Wq : ((which == 1) ? Wk : Wv);
        dh  = (which == 0) ? wqh : ((which == 1) ? wkh : wvh);
        dl  = (which == 0) ? wql : ((which == 1) ? wkl : wvl);
    }
    float4 v = *(const float4*)(src + off);
    ushort4 h, l;
    h.x = bf16_rne(v.x); l.x = bf16_rne(v.x - bf16_to_f32(h.x));
    h.y = bf16_rne(v.y); l.y = bf16_rne(v.y - bf16_to_f32(h.y));
    h.z = bf16_rne(v.z); l.z = bf16_rne(v.z - bf16_to_f32(h.z));
    h.w = bf16_rne(v.w); l.w = bf16_rne(v.w - bf16_to_f32(h.w));
    *(ushort4*)(dh + off) = h;
    *(ushort4*)(dl + off) = l;
}

// ---------------------------------------------------------------------------
// Kernel 1: QKV projection via split-bf16 MFMA (the proven scores body;
// identical GEMM shape: A=x rows [m][c], B=W rows [w][c], K=C=256).
// r = relu(x·Wᵀ + b); q,k stored split-bf16, v stored fp32.
// grid (128 m-blocks, 6): blockIdx.y -> which = y>>1, w-half = (y&1)*128.
// ---------------------------------------------------------------------------
__global__ __launch_bounds__(256) void qkv_mfma_kernel(
    const ushort* __restrict__ xh, const ushort* __restrict__ xl,
    const ushort* __restrict__ wqh, const ushort* __restrict__ wql,
    const ushort* __restrict__ wkh, const ushort* __restrict__ wkl,
    const ushort* __restrict__ wvh, const ushort* __restrict__ wvl,
    const float* __restrict__ bq, const float* __restrict__ bk,
    const float* __restrict__ bv,
    float* __restrict__ v32,
    ushort* __restrict__ qhi, ushort* __restrict__ qlo,
    ushort* __restrict__ khi, ushort* __restrict__ klo)
{
    __shared__ ushort lah[4096], lal[4096], lbh[4096], lbl[4096];

    const int tid = threadIdx.x;
    const int m0 = blockIdx.x * 128;
    const int yy = blockIdx.y;
    const int which = yy >> 1;
    const int w0 = (yy & 1) * 128;

    const ushort* wh_ = (which == 0) ? wqh : ((which == 1) ? wkh : wvh);
    const ushort* wl_ = (which == 0) ? wql : ((which == 1) ? wkl : wvl);
    const float*  bm  = (which == 0) ? bq  : ((which == 1) ? bk  : bv);

    const ushort* ah_ = xh + (size_t)m0 * Cc;
    const ushort* al_ = xl + (size_t)m0 * Cc;
    const ushort* bh_ = wh_ + (size_t)w0 * Cc;
    const ushort* bl_ = wl_ + (size_t)w0 * Cc;

    const int wave = tid >> 6, lane = tid & 63;
    const int wy = wave >> 1, wx = wave & 1;
    const int lrow = lane & 15, lg = lane >> 4;

    f32x4 acc[4][4];
    #pragma unroll
    for (int a = 0; a < 4; ++a)
        #pragma unroll
        for (int c = 0; c < 4; ++c) acc[a][c] = (f32x4){0.f, 0.f, 0.f, 0.f};

    const int cg = tid & 3;
    const int cr0 = tid >> 2;

    for (int kc = 0; kc < Cc; kc += 32) {
        #pragma unroll
        for (int h = 0; h < 2; ++h) {
            int r = cr0 + h * 64;
            int gg = cg ^ ((r >> 1) & 3);
            int li = r * 32 + gg * 8;
            size_t go = (size_t)r * Cc + kc + cg * 8;
            *(bf16x8*)&lah[li] = *(const bf16x8*)(ah_ + go);
            *(bf16x8*)&lal[li] = *(const bf16x8*)(al_ + go);
            *(bf16x8*)&lbh[li] = *(const bf16x8*)(bh_ + go);
            *(bf16x8*)&lbl[li] = *(const bf16x8*)(bl_ + go);
        }
        __syncthreads();

        bf16x8 ah[4], al[4], bh[4], bl[4];
        #pragma unroll
        for (int t = 0; t < 4; ++t) {
            int ra = wy * 64 + t * 16 + lrow;
            int ia = ra * 32 + ((lg ^ ((ra >> 1) & 3)) * 8);
            ah[t] = *(const bf16x8*)&lah[ia];
            al[t] = *(const bf16x8*)&lal[ia];
            int rb = wx * 64 + t * 16 + lrow;
            int ib = rb * 32 + ((lg ^ ((rb >> 1) & 3)) * 8);
            bh[t] = *(const bf16x8*)&lbh[ib];
            bl[t] = *(const bf16x8*)&lbl[ib];
        }
        #pragma unroll
        for (int jt = 0; jt < 4; ++jt)
            #pragma unroll
            for (int it = 0; it < 4; ++it) {
                acc[jt][it] = __builtin_amdgcn_mfma_f32_16x16x32_bf16(ah[jt], bh[it], acc[jt][it], 0, 0, 0);
                acc[jt][it] = __builtin_amdgcn_mfma_f32_16x16x32_bf16(ah[jt], bl[it], acc[jt][it], 0, 0, 0);
                acc[jt][it] = __builtin_amdgcn_mfma_f32_16x16x32_bf16(al[jt], bh[it], acc[jt][it], 0, 0, 0);
            }
        __syncthreads();
    }

    // Epilogue: out[m][w] = relu(acc + bias[w]); split-store (q,k) / fp32 (v).
    // m = m0 + wy*64 + jt*16 + lg*4 + rg (A side); w = w0 + wx*64 + it*16 + lrow.
    ushort* hp = (which == 0) ? qhi : khi;
    ushort* lp = (which == 0) ? qlo : klo;
    #pragma unroll
    for (int it = 0; it < 4; ++it) {
        const int w = w0 + wx * 64 + it * 16 + lrow;
        const float bias = bm[w];
        #pragma unroll
        for (int jt = 0; jt < 4; ++jt) {
            const int mb = m0 + wy * 64 + jt * 16 + lg * 4;
            #pragma unroll
            for (int rg = 0; rg < 4; ++rg) {
                float val = fmaxf(acc[jt][it][rg] + bias, 0.f);
                size_t o = (size_t)(mb + rg) * Ww + w;
                if (which == 2) {
                    v32[o] = val;
                } else {
                    ushort h = bf16_rne(val);
                    hp[o] = h;
                    lp[o] = bf16_rne(val - bf16_to_f32(h));
                }
            }
        }
    }
}

// ---------------------------------------------------------------------------
// Kernel 2: E[b][i][j] = bf16( exp(scale * sum_w k[b,j,w]*q[b,i,w]) )
// + D[j] = sum_i e_rounded (atomicAdd into pre-zeroed Dp). (unchanged, proven)
// ---------------------------------------------------------------------------
__global__ __launch_bounds__(256) void scores_mfma_kernel(
    const ushort* __restrict__ qhi, const ushort* __restrict__ qlo,
    const ushort* __restrict__ khi, const ushort* __restrict__ klo,
    ushort* __restrict__ eh, float* __restrict__ dpart)
{
    __shared__ ushort lkh[4096], lkl[4096], lqh[4096], lql[4096];

    const int tid = threadIdx.x;
    const int i0 = blockIdx.x * 128;
    const int j0 = blockIdx.y * 128;
    const int b  = blockIdx.z;

    const ushort* kh = khi + ((size_t)b * Nn + j0) * Ww;
    const ushort* kl = klo + ((size_t)b * Nn + j0) * Ww;
    const ushort* qh = qhi + ((size_t)b * Nn + i0) * Ww;
    const ushort* ql = qlo + ((size_t)b * Nn + i0) * Ww;

    const int wave = tid >> 6, lane = tid & 63;
    const int wy = wave >> 1, wx = wave & 1;
    const int lrow = lane & 15, lg = lane >> 4;

    f32x4 acc[4][4];
    #pragma unroll
    for (int a = 0; a < 4; ++a)
        #pragma unroll
        for (int c = 0; c < 4; ++c) acc[a][c] = (f32x4){0.f, 0.f, 0.f, 0.f};

    const int cg = tid & 3;
    const int cr0 = tid >> 2;

    for (int kc = 0; kc < Ww; kc += 32) {
        #pragma unroll
        for (int h = 0; h < 2; ++h) {
            int r = cr0 + h * 64;
            int gg = cg ^ ((r >> 1) & 3);
            int li = r * 32 + gg * 8;
            size_t go = (size_t)r * Ww + kc + cg * 8;
            *(bf16x8*)&lkh[li] = *(const bf16x8*)(kh + go);
            *(bf16x8*)&lkl[li] = *(const bf16x8*)(kl + go);
            *(bf16x8*)&lqh[li] = *(const bf16x8*)(qh + go);
            *(bf16x8*)&lql[li] = *(const bf16x8*)(ql + go);
        }
        __syncthreads();

        bf16x8 ah[4], al[4], bh[4], bl[4];
        #pragma unroll
        for (int t = 0; t < 4; ++t) {
            int ra = wy * 64 + t * 16 + lrow;
            int ia = ra * 32 + ((lg ^ ((ra >> 1) & 3)) * 8);
            ah[t] = *(const bf16x8*)&lkh[ia];
            al[t] = *(const bf16x8*)&lkl[ia];
            int rb = wx * 64 + t * 16 + lrow;
            int ib = rb * 32 + ((lg ^ ((rb >> 1) & 3)) * 8);
            bh[t] = *(const bf16x8*)&lqh[ib];
            bl[t] = *(const bf16x8*)&lql[ib];
        }
        #pragma unroll
        for (int jt = 0; jt < 4; ++jt)
            #pragma unroll
            for (int it = 0; it < 4; ++it) {
                acc[jt][it] = __builtin_amdgcn_mfma_f32_16x16x32_bf16(ah[jt], bh[it], acc[jt][it], 0, 0, 0);
                acc[jt][it] = __builtin_amdgcn_mfma_f32_16x16x32_bf16(ah[jt], bl[it], acc[jt][it], 0, 0, 0);
                acc[jt][it] = __builtin_amdgcn_mfma_f32_16x16x32_bf16(al[jt], bh[it], acc[jt][it], 0, 0, 0);
            }
        __syncthreads();
    }

    // Epilogue: e = exp(scale*s); store E[i][j] plain bf16; D from rounded e.
    const float scale = 0.02209708691207961f;  // 1/sqrt(2048)
    ushort* ehb = eh + (size_t)b * Nn * Nn;
    float* dpb  = dpart + (size_t)b * Nn;

    float esum[4][4];
    #pragma unroll
    for (int jt = 0; jt < 4; ++jt)
        #pragma unroll
        for (int rg = 0; rg < 4; ++rg) esum[jt][rg] = 0.f;

    #pragma unroll
    for (int jt = 0; jt < 4; ++jt) {
        const int jb = j0 + wy * 64 + jt * 16 + lg * 4;   // D-row (A=k side)
        #pragma unroll
        for (int it = 0; it < 4; ++it) {
            const int i = i0 + wx * 64 + it * 16 + lrow;  // D-col (B=q side)
            ushort4 h4;
            #pragma unroll
            for (int rg = 0; rg < 4; ++rg) {
                float e = __expf(acc[jt][it][rg] * scale);
                ushort hh = bf16_rne(e);
                (&h4.x)[rg] = hh;
                esum[jt][rg] += bf16_to_f32(hh);
            }
            *(ushort4*)(ehb + (size_t)i * Nn + jb) = h4;
        }
    }
    #pragma unroll
    for (int jt = 0; jt < 4; ++jt)
        #pragma unroll
        for (int rg = 0; rg < 4; ++rg) {
            float v = esum[jt][rg];
            v += __shfl_xor(v, 1);
            v += __shfl_xor(v, 2);
            v += __shfl_xor(v, 4);
            v += __shfl_xor(v, 8);
            if (lrow == 0)
                atomicAdd(dpb + j0 + wy * 64 + jt * 16 + lg * 4 + rg, v);
        }
}

// ---------------------------------------------------------------------------
// Kernel 2.5: vT split-transpose WITH 1/D fold. (unchanged, proven)
// ---------------------------------------------------------------------------
__global__ __launch_bounds__(256) void vt_kernel(
    const float* __restrict__ v32, const float* __restrict__ dpart,
    ushort* __restrict__ vthi, ushort* __restrict__ vtlo)
{
    __shared__ ushort Thi[64*66], Tlo[64*66];
    const int tid = threadIdx.x;
    const int j0 = blockIdx.x * 64;
    const int w0 = blockIdx.y * 64;
    const int b  = blockIdx.z;
    const float* vb = v32 + (size_t)b * Nn * Ww;
    const float* dpb = dpart + (size_t)b * Nn;

    #pragma unroll
    for (int r = 0; r < 4; ++r) {
        int j  = (tid >> 4) + r * 16;
        int wl = (tid & 15) * 4;
        float invd = 1.0f / dpb[j0 + j];
        float4 tv = *(const float4*)(vb + (size_t)(j0 + j) * Ww + w0 + wl);
        float f[4] = {tv.x * invd, tv.y * invd, tv.z * invd, tv.w * invd};
        #pragma unroll
        for (int c = 0; c < 4; ++c) {
            ushort h = bf16_rne(f[c]);
            Thi[(wl + c) * 66 + j] = h;
            Tlo[(wl + c) * 66 + j] = bf16_rne(f[c] - bf16_to_f32(h));
        }
    }
    __syncthreads();
    {
        int wl = tid >> 2, jc = (tid & 3) * 16;
        size_t go = ((size_t)b * Ww + w0 + wl) * Nn + j0 + jc;
        uint tH[8], tL[8];
        #pragma unroll
        for (int u = 0; u < 8; ++u) {
            tH[u] = *(const uint*)&Thi[wl * 66 + jc + u * 2];
            tL[u] = *(const uint*)&Tlo[wl * 66 + jc + u * 2];
        }
        #pragma unroll
        for (int u = 0; u < 2; ++u) {
            uint4 hh; hh.x = tH[u*4+0]; hh.y = tH[u*4+1]; hh.z = tH[u*4+2]; hh.w = tH[u*4+3];
            uint4 ll; ll.x = tL[u*4+0]; ll.y = tL[u*4+1]; ll.z = tL[u*4+2]; ll.w = tL[u*4+3];
            *(uint4*)(vthi + go + u * 8) = hh;
            *(uint4*)(vtlo + go + u * 8) = ll;
        }
    }
}

// ---------------------------------------------------------------------------
// Kernel 3: PV. part[kz][b,i,w] = sum_{j in kz-half} E[i][j] * v'[j][w].
// (unchanged, proven: conflict-0 stride-40 staging, T14 prefetch, ksplit 2)
// ---------------------------------------------------------------------------
__global__ __launch_bounds__(256) void pv_mfma_kernel(
    const ushort* __restrict__ eh,
    const ushort* __restrict__ vthi, const ushort* __restrict__ vtlo,
    float* __restrict__ part)
{
    __shared__ alignas(16) ushort Ah[128*40];            // E tile  [i][j]
    __shared__ alignas(16) ushort Bh[64*40], Bl[64*40];  // v' tile [w][j]

    const int tid = threadIdx.x;
    const int i0 = blockIdx.x * 128;
    const int wt = blockIdx.y & 3, kz = blockIdx.y >> 2;
    const int w0 = wt * 64;
    const int b  = blockIdx.z;

    const ushort* ehb = eh + (size_t)b * Nn * Nn;
    const ushort* vhb = vthi + (size_t)b * Ww * Nn;
    const ushort* vlb = vtlo + (size_t)b * Ww * Nn;

    const int wave = tid >> 6, lane = tid & 63;
    const int wy = wave >> 1, wx = wave & 1;    // i-half(64) / w-half(32)
    const int lr = lane & 15, lg = lane >> 4;

    f32x4 acc[4][2];
    #pragma unroll
    for (int a = 0; a < 4; ++a)
        #pragma unroll
        for (int c = 0; c < 2; ++c) acc[a][c] = (f32x4){0.f, 0.f, 0.f, 0.f};

    const bool isA = tid < 128;
    const int srow = isA ? tid : (tid & 63);
    const ushort* gsrc = isA ? ehb : ((tid & 64) ? vlb : vhb);
    const size_t goff0 = isA
        ? ((size_t)(i0 + srow) * Nn + (size_t)kz * 1024)
        : ((size_t)(w0 + srow) * Nn + (size_t)kz * 1024);
    ushort* ldst = isA ? &Ah[srow * 40] : ((tid & 64) ? &Bl[srow * 40] : &Bh[srow * 40]);

    bf16x8 r0 = *(const bf16x8*)(gsrc + goff0);
    bf16x8 r1 = *(const bf16x8*)(gsrc + goff0 + 8);
    bf16x8 r2 = *(const bf16x8*)(gsrc + goff0 + 16);
    bf16x8 r3 = *(const bf16x8*)(gsrc + goff0 + 24);

    for (int ks = 0; ks < 32; ++ks) {
        *(bf16x8*)(ldst)      = r0;
        *(bf16x8*)(ldst + 8)  = r1;
        *(bf16x8*)(ldst + 16) = r2;
        *(bf16x8*)(ldst + 24) = r3;
        __syncthreads();

        if (ks < 31) {
            const size_t go = goff0 + (ks + 1) * 32;
            r0 = *(const bf16x8*)(gsrc + go);
            r1 = *(const bf16x8*)(gsrc + go + 8);
            r2 = *(const bf16x8*)(gsrc + go + 16);
            r3 = *(const bf16x8*)(gsrc + go + 24);
        }

        bf16x8 af[4], bfh[2], bfl[2];
        #pragma unroll
        for (int t = 0; t < 4; ++t)
            af[t] = *(const bf16x8*)&Ah[(wy * 64 + t * 16 + lr) * 40 + lg * 8];
        #pragma unroll
        for (int t = 0; t < 2; ++t) {
            const int br = (wx * 32 + t * 16 + lr) * 40 + lg * 8;
            bfh[t] = *(const bf16x8*)&Bh[br];
            bfl[t] = *(const bf16x8*)&Bl[br];
        }
        #pragma unroll
        for (int ia = 0; ia < 4; ++ia)
            #pragma unroll
            for (int ib = 0; ib < 2; ++ib) {
                acc[ia][ib] = __builtin_amdgcn_mfma_f32_16x16x32_bf16(af[ia], bfh[ib], acc[ia][ib], 0, 0, 0);
                acc[ia][ib] = __builtin_amdgcn_mfma_f32_16x16x32_bf16(af[ia], bfl[ib], acc[ia][ib], 0, 0, 0);
            }
        __syncthreads();
    }

    float* pout = part + (size_t)kz * Mtot * Ww;
    #pragma unroll
    for (int ia = 0; ia < 4; ++ia) {
        const int ibase = i0 + wy * 64 + ia * 16 + lg * 4;
        #pragma unroll
        for (int ib = 0; ib < 2; ++ib) {
            const int w = w0 + wx * 32 + ib * 16 + lr;
            #pragma unroll
            for (int rg = 0; rg < 4; ++rg)
                pout[((size_t)(b * Nn + ibase + rg)) * Ww + w] = acc[ia][ib][rg];
        }
    }
}

// ---------------------------------------------------------------------------
// Kernel 4: out = part0 + part1 + q (q from split bf16). grid 4096, blk 256.
// ---------------------------------------------------------------------------
__global__ __launch_bounds__(256) void qadd_kernel(
    const float* __restrict__ part,
    const ushort* __restrict__ qhi, const ushort* __restrict__ qlo,
    float* __restrict__ out)
{
    const size_t g4 = ((size_t)blockIdx.x * 256 + threadIdx.x) * 4;
    float4 p0 = *(const float4*)(part + g4);
    float4 p1 = *(const float4*)(part + (size_t)Mtot * Ww + g4);
    ushort4 h = *(const ushort4*)(qhi + g4);
    ushort4 l = *(const ushort4*)(qlo + g4);
    float4 o;
    o.x = p0.x + p1.x + bf16_to_f32(h.x) + bf16_to_f32(l.x);
    o.y = p0.y + p1.y + bf16_to_f32(h.y) + bf16_to_f32(l.y);
    o.z = p0.z + p1.z + bf16_to_f32(h.z) + bf16_to_f32(l.z);
    o.w = p0.w + p1.w + bf16_to_f32(h.w) + bf16_to_f32(l.w);
    *(float4*)(out + g4) = o;
}

// ---------------------------------------------------------------------------
// Launch. ws: v32 f32 [16MB] | qhi,qlo,khi,klo [32MB] | Eh [64MB] |
// part [32MB] | Dp [64KB] | xh,xl [16MB] | W splits [0.75MB] = ~161 MiB.
// vthi/vtlo reuse khi/klo after scores consumed k.
// ---------------------------------------------------------------------------
extern "C" void kernel_launch(void* const* d_in, const int* in_sizes, int n_in,
                              void* d_out, int out_size, void* d_ws, size_t ws_size,
                              hipStream_t stream) {
    const float* x  = (const float*)d_in[0];
    const float* Wq = (const float*)d_in[1];
    const float* bq = (const float*)d_in[2];
    const float* Wk = (const float*)d_in[3];
    const float* bk = (const float*)d_in[4];
    const float* Wv = (const float*)d_in[5];
    const float* bv = (const float*)d_in[6];
    // d_in[7] = valid_len (unused by the reference forward)
    float* out = (float*)d_out;

    float*  v32 = (float*)d_ws;
    ushort* qhi = (ushort*)(v32 + (size_t)Mtot * Ww);
    ushort* qlo = qhi + (size_t)Mtot * Ww;
    ushort* khi = qlo + (size_t)Mtot * Ww;
    ushort* klo = khi + (size_t)Mtot * Ww;
    ushort* eh  = klo + (size_t)Mtot * Ww;
    float*  part = (float*)(eh + (size_t)Bb * Nn * Nn);
    float*  dpart = part + (size_t)2 * Mtot * Ww;
    ushort* xh  = (ushort*)(dpart + Bb * Nn);
    ushort* xl  = xh + (size_t)Mtot * Cc;
    ushort* wqh = xl + (size_t)Mtot * Cc;
    ushort* wql = wqh + Ww * Cc;
    ushort* wkh = wql + Ww * Cc;
    ushort* wkl = wkh + Ww * Cc;
    ushort* wvh = wkl + Ww * Cc;
    ushort* wvl = wvh + Ww * Cc;
    ushort* vthi = khi;   // reuse after scores_mfma consumed k
    ushort* vtlo = klo;

    hipMemsetAsync(dpart, 0, (size_t)Bb * Nn * sizeof(float), stream);
    prep_kernel<<<dim3(4288), 256, 0, stream>>>(x, Wq, Wk, Wv, xh, xl,
                                                wqh, wql, wkh, wkl, wvh, wvl);
    qkv_mfma_kernel<<<dim3(128, 6), 256, 0, stream>>>(xh, xl, wqh, wql, wkh, wkl,
                                                      wvh, wvl, bq, bk, bv,
                                                      v32, qhi, qlo, khi, klo);
    scores_mfma_kernel<<<dim3(16, 16, 8), 256, 0, stream>>>(qhi, qlo, khi, klo, eh, dpart);
    vt_kernel<<<dim3(32, 4, 8), 256, 0, stream>>>(v32, dpart, vthi, vtlo);
    pv_mfma_kernel<<<dim3(16, 8, 8), 256, 0, stream>>>(eh, vthi, vtlo, part);
    qadd_kernel<<<dim3(4096), 256, 0, stream>>>(part, qhi, qlo, out);
}

// Round 11
// 257.734 us; speedup vs baseline: 1.4786x; 1.1110x over previous
//
#include <hip/hip_runtime.h>
#include <math.h>

// Problem constants (reference: B=8, N=2048, C=256, W=256)
#define Bb 8
#define Nn 2048
#define Cc 256
#define Ww 256
#define Mtot (Bb*Nn)   // 16384

typedef __attribute__((ext_vector_type(8))) short bf16x8;
typedef __attribute__((ext_vector_type(4))) float f32x4;

__device__ __forceinline__ ushort bf16_rne(float f) {
    uint u = __float_as_uint(f);
    return (ushort)((u + 0x7FFFu + ((u >> 16) & 1u)) >> 16);
}
__device__ __forceinline__ float bf16_to_f32(ushort h) {
    return __uint_as_float(((uint)h) << 16);
}

// ---------------------------------------------------------------------------
// Kernel 0: split x and Wq/Wk/Wv into bf16 hi/lo. (unchanged, proven)
// ---------------------------------------------------------------------------
__global__ __launch_bounds__(256) void prep_kernel(
    const float* __restrict__ x,
    const float* __restrict__ Wq, const float* __restrict__ Wk,
    const float* __restrict__ Wv,
    ushort* __restrict__ xh, ushort* __restrict__ xl,
    ushort* __restrict__ wqh, ushort* __restrict__ wql,
    ushort* __restrict__ wkh, ushort* __restrict__ wkl,
    ushort* __restrict__ wvh, ushort* __restrict__ wvl)
{
    const int tid = threadIdx.x;
    const float* src;
    ushort *dh, *dl;
    size_t off;
    if (blockIdx.x < 4096) {
        off = ((size_t)blockIdx.x * 256 + tid) * 4;
        src = x; dh = xh; dl = xl;
    } else {
        size_t s = ((size_t)(blockIdx.x - 4096) * 256 + tid) * 4;
        int which = (int)(s >> 16);
        off = s & 65535u;
        src = (which == 0) ? Wq : ((which == 1) ? Wk : Wv);
        dh  = (which == 0) ? wqh : ((which == 1) ? wkh : wvh);
        dl  = (which == 0) ? wql : ((which == 1) ? wkl : wvl);
    }
    float4 v = *(const float4*)(src + off);
    ushort4 h, l;
    h.x = bf16_rne(v.x); l.x = bf16_rne(v.x - bf16_to_f32(h.x));
    h.y = bf16_rne(v.y); l.y = bf16_rne(v.y - bf16_to_f32(h.y));
    h.z = bf16_rne(v.z); l.z = bf16_rne(v.z - bf16_to_f32(h.z));
    h.w = bf16_rne(v.w); l.w = bf16_rne(v.w - bf16_to_f32(h.w));
    *(ushort4*)(dh + off) = h;
    *(ushort4*)(dl + off) = l;
}

// ---------------------------------------------------------------------------
// Kernel 1: QKV projection via split-bf16 MFMA + T14 reg-prefetch.
// grid (128, 6): which = y>>1, w-half = (y&1)*128.
// ---------------------------------------------------------------------------
__global__ __launch_bounds__(256) void qkv_mfma_kernel(
    const ushort* __restrict__ xh, const ushort* __restrict__ xl,
    const ushort* __restrict__ wqh, const ushort* __restrict__ wql,
    const ushort* __restrict__ wkh, const ushort* __restrict__ wkl,
    const ushort* __restrict__ wvh, const ushort* __restrict__ wvl,
    const float* __restrict__ bq, const float* __restrict__ bk,
    const float* __restrict__ bv,
    float* __restrict__ v32,
    ushort* __restrict__ qhi, ushort* __restrict__ qlo,
    ushort* __restrict__ khi, ushort* __restrict__ klo)
{
    __shared__ ushort lah[4096], lal[4096], lbh[4096], lbl[4096];

    const int tid = threadIdx.x;
    const int m0 = blockIdx.x * 128;
    const int yy = blockIdx.y;
    const int which = yy >> 1;
    const int w0 = (yy & 1) * 128;

    const ushort* wh_ = (which == 0) ? wqh : ((which == 1) ? wkh : wvh);
    const ushort* wl_ = (which == 0) ? wql : ((which == 1) ? wkl : wvl);
    const float*  bm  = (which == 0) ? bq  : ((which == 1) ? bk  : bv);

    const ushort* ah_ = xh + (size_t)m0 * Cc;
    const ushort* al_ = xl + (size_t)m0 * Cc;
    const ushort* bh_ = wh_ + (size_t)w0 * Cc;
    const ushort* bl_ = wl_ + (size_t)w0 * Cc;

    const int wave = tid >> 6, lane = tid & 63;
    const int wy = wave >> 1, wx = wave & 1;
    const int lrow = lane & 15, lg = lane >> 4;

    f32x4 acc[4][4];
    #pragma unroll
    for (int a = 0; a < 4; ++a)
        #pragma unroll
        for (int c = 0; c < 4; ++c) acc[a][c] = (f32x4){0.f, 0.f, 0.f, 0.f};

    const int cg = tid & 3;
    const int cr0 = tid >> 2;

    // T14 prologue: K-step 0 into regs
    bf16x8 sah[2], sal[2], sbh[2], sbl[2];
    #pragma unroll
    for (int h = 0; h < 2; ++h) {
        int r = cr0 + h * 64;
        size_t go = (size_t)r * Cc + cg * 8;
        sah[h] = *(const bf16x8*)(ah_ + go);
        sal[h] = *(const bf16x8*)(al_ + go);
        sbh[h] = *(const bf16x8*)(bh_ + go);
        sbl[h] = *(const bf16x8*)(bl_ + go);
    }

    for (int kc = 0; kc < Cc; kc += 32) {
        #pragma unroll
        for (int h = 0; h < 2; ++h) {
            int r = cr0 + h * 64;
            int gg = cg ^ ((r >> 1) & 3);
            int li = r * 32 + gg * 8;
            *(bf16x8*)&lah[li] = sah[h];
            *(bf16x8*)&lal[li] = sal[h];
            *(bf16x8*)&lbh[li] = sbh[h];
            *(bf16x8*)&lbl[li] = sbl[h];
        }
        __syncthreads();

        // issue next K-step's loads; latency hides under frag reads + MFMA
        if (kc + 32 < Cc) {
            #pragma unroll
            for (int h = 0; h < 2; ++h) {
                int r = cr0 + h * 64;
                size_t go = (size_t)r * Cc + kc + 32 + cg * 8;
                sah[h] = *(const bf16x8*)(ah_ + go);
                sal[h] = *(const bf16x8*)(al_ + go);
                sbh[h] = *(const bf16x8*)(bh_ + go);
                sbl[h] = *(const bf16x8*)(bl_ + go);
            }
        }

        bf16x8 ah[4], al[4], bh[4], bl[4];
        #pragma unroll
        for (int t = 0; t < 4; ++t) {
            int ra = wy * 64 + t * 16 + lrow;
            int ia = ra * 32 + ((lg ^ ((ra >> 1) & 3)) * 8);
            ah[t] = *(const bf16x8*)&lah[ia];
            al[t] = *(const bf16x8*)&lal[ia];
            int rb = wx * 64 + t * 16 + lrow;
            int ib = rb * 32 + ((lg ^ ((rb >> 1) & 3)) * 8);
            bh[t] = *(const bf16x8*)&lbh[ib];
            bl[t] = *(const bf16x8*)&lbl[ib];
        }
        #pragma unroll
        for (int jt = 0; jt < 4; ++jt)
            #pragma unroll
            for (int it = 0; it < 4; ++it) {
                acc[jt][it] = __builtin_amdgcn_mfma_f32_16x16x32_bf16(ah[jt], bh[it], acc[jt][it], 0, 0, 0);
                acc[jt][it] = __builtin_amdgcn_mfma_f32_16x16x32_bf16(ah[jt], bl[it], acc[jt][it], 0, 0, 0);
                acc[jt][it] = __builtin_amdgcn_mfma_f32_16x16x32_bf16(al[jt], bh[it], acc[jt][it], 0, 0, 0);
            }
        __syncthreads();
    }

    // Epilogue: out[m][w] = relu(acc + bias[w]); split-store (q,k) / fp32 (v).
    ushort* hp = (which == 0) ? qhi : khi;
    ushort* lp = (which == 0) ? qlo : klo;
    #pragma unroll
    for (int it = 0; it < 4; ++it) {
        const int w = w0 + wx * 64 + it * 16 + lrow;
        const float bias = bm[w];
        #pragma unroll
        for (int jt = 0; jt < 4; ++jt) {
            const int mb = m0 + wy * 64 + jt * 16 + lg * 4;
            #pragma unroll
            for (int rg = 0; rg < 4; ++rg) {
                float val = fmaxf(acc[jt][it][rg] + bias, 0.f);
                size_t o = (size_t)(mb + rg) * Ww + w;
                if (which == 2) {
                    v32[o] = val;
                } else {
                    ushort h = bf16_rne(val);
                    hp[o] = h;
                    lp[o] = bf16_rne(val - bf16_to_f32(h));
                }
            }
        }
    }
}

// ---------------------------------------------------------------------------
// Kernel 2: E[b][i][j] = bf16(exp(scale*sum_w k·q)) + D[j] partial sums.
// Proven body + T14 reg-prefetch (numerics identical to round 10).
// ---------------------------------------------------------------------------
__global__ __launch_bounds__(256) void scores_mfma_kernel(
    const ushort* __restrict__ qhi, const ushort* __restrict__ qlo,
    const ushort* __restrict__ khi, const ushort* __restrict__ klo,
    ushort* __restrict__ eh, float* __restrict__ dpart)
{
    __shared__ ushort lkh[4096], lkl[4096], lqh[4096], lql[4096];

    const int tid = threadIdx.x;
    const int i0 = blockIdx.x * 128;
    const int j0 = blockIdx.y * 128;
    const int b  = blockIdx.z;

    const ushort* kh = khi + ((size_t)b * Nn + j0) * Ww;
    const ushort* kl = klo + ((size_t)b * Nn + j0) * Ww;
    const ushort* qh = qhi + ((size_t)b * Nn + i0) * Ww;
    const ushort* ql = qlo + ((size_t)b * Nn + i0) * Ww;

    const int wave = tid >> 6, lane = tid & 63;
    const int wy = wave >> 1, wx = wave & 1;
    const int lrow = lane & 15, lg = lane >> 4;

    f32x4 acc[4][4];
    #pragma unroll
    for (int a = 0; a < 4; ++a)
        #pragma unroll
        for (int c = 0; c < 4; ++c) acc[a][c] = (f32x4){0.f, 0.f, 0.f, 0.f};

    const int cg = tid & 3;
    const int cr0 = tid >> 2;

    // T14 prologue
    bf16x8 skh[2], skl[2], sqh[2], sql[2];
    #pragma unroll
    for (int h = 0; h < 2; ++h) {
        int r = cr0 + h * 64;
        size_t go = (size_t)r * Ww + cg * 8;
        skh[h] = *(const bf16x8*)(kh + go);
        skl[h] = *(const bf16x8*)(kl + go);
        sqh[h] = *(const bf16x8*)(qh + go);
        sql[h] = *(const bf16x8*)(ql + go);
    }

    for (int kc = 0; kc < Ww; kc += 32) {
        #pragma unroll
        for (int h = 0; h < 2; ++h) {
            int r = cr0 + h * 64;
            int gg = cg ^ ((r >> 1) & 3);
            int li = r * 32 + gg * 8;
            *(bf16x8*)&lkh[li] = skh[h];
            *(bf16x8*)&lkl[li] = skl[h];
            *(bf16x8*)&lqh[li] = sqh[h];
            *(bf16x8*)&lql[li] = sql[h];
        }
        __syncthreads();

        if (kc + 32 < Ww) {
            #pragma unroll
            for (int h = 0; h < 2; ++h) {
                int r = cr0 + h * 64;
                size_t go = (size_t)r * Ww + kc + 32 + cg * 8;
                skh[h] = *(const bf16x8*)(kh + go);
                skl[h] = *(const bf16x8*)(kl + go);
                sqh[h] = *(const bf16x8*)(qh + go);
                sql[h] = *(const bf16x8*)(ql + go);
            }
        }

        bf16x8 ah[4], al[4], bh[4], bl[4];
        #pragma unroll
        for (int t = 0; t < 4; ++t) {
            int ra = wy * 64 + t * 16 + lrow;
            int ia = ra * 32 + ((lg ^ ((ra >> 1) & 3)) * 8);
            ah[t] = *(const bf16x8*)&lkh[ia];
            al[t] = *(const bf16x8*)&lkl[ia];
            int rb = wx * 64 + t * 16 + lrow;
            int ib = rb * 32 + ((lg ^ ((rb >> 1) & 3)) * 8);
            bh[t] = *(const bf16x8*)&lqh[ib];
            bl[t] = *(const bf16x8*)&lql[ib];
        }
        #pragma unroll
        for (int jt = 0; jt < 4; ++jt)
            #pragma unroll
            for (int it = 0; it < 4; ++it) {
                acc[jt][it] = __builtin_amdgcn_mfma_f32_16x16x32_bf16(ah[jt], bh[it], acc[jt][it], 0, 0, 0);
                acc[jt][it] = __builtin_amdgcn_mfma_f32_16x16x32_bf16(ah[jt], bl[it], acc[jt][it], 0, 0, 0);
                acc[jt][it] = __builtin_amdgcn_mfma_f32_16x16x32_bf16(al[jt], bh[it], acc[jt][it], 0, 0, 0);
            }
        __syncthreads();
    }

    // Epilogue: e = exp(scale*s); store E[i][j] plain bf16; D from rounded e.
    const float scale = 0.02209708691207961f;  // 1/sqrt(2048)
    ushort* ehb = eh + (size_t)b * Nn * Nn;
    float* dpb  = dpart + (size_t)b * Nn;

    float esum[4][4];
    #pragma unroll
    for (int jt = 0; jt < 4; ++jt)
        #pragma unroll
        for (int rg = 0; rg < 4; ++rg) esum[jt][rg] = 0.f;

    #pragma unroll
    for (int jt = 0; jt < 4; ++jt) {
        const int jb = j0 + wy * 64 + jt * 16 + lg * 4;   // D-row (A=k side)
        #pragma unroll
        for (int it = 0; it < 4; ++it) {
            const int i = i0 + wx * 64 + it * 16 + lrow;  // D-col (B=q side)
            ushort4 h4;
            #pragma unroll
            for (int rg = 0; rg < 4; ++rg) {
                float e = __expf(acc[jt][it][rg] * scale);
                ushort hh = bf16_rne(e);
                (&h4.x)[rg] = hh;
                esum[jt][rg] += bf16_to_f32(hh);
            }
            *(ushort4*)(ehb + (size_t)i * Nn + jb) = h4;
        }
    }
    #pragma unroll
    for (int jt = 0; jt < 4; ++jt)
        #pragma unroll
        for (int rg = 0; rg < 4; ++rg) {
            float v = esum[jt][rg];
            v += __shfl_xor(v, 1);
            v += __shfl_xor(v, 2);
            v += __shfl_xor(v, 4);
            v += __shfl_xor(v, 8);
            if (lrow == 0)
                atomicAdd(dpb + j0 + wy * 64 + jt * 16 + lg * 4 + rg, v);
        }
}

// ---------------------------------------------------------------------------
// Kernel 2.5: vT split-transpose WITH 1/D fold. (unchanged, proven)
// ---------------------------------------------------------------------------
__global__ __launch_bounds__(256) void vt_kernel(
    const float* __restrict__ v32, const float* __restrict__ dpart,
    ushort* __restrict__ vthi, ushort* __restrict__ vtlo)
{
    __shared__ ushort Thi[64*66], Tlo[64*66];
    const int tid = threadIdx.x;
    const int j0 = blockIdx.x * 64;
    const int w0 = blockIdx.y * 64;
    const int b  = blockIdx.z;
    const float* vb = v32 + (size_t)b * Nn * Ww;
    const float* dpb = dpart + (size_t)b * Nn;

    #pragma unroll
    for (int r = 0; r < 4; ++r) {
        int j  = (tid >> 4) + r * 16;
        int wl = (tid & 15) * 4;
        float invd = 1.0f / dpb[j0 + j];
        float4 tv = *(const float4*)(vb + (size_t)(j0 + j) * Ww + w0 + wl);
        float f[4] = {tv.x * invd, tv.y * invd, tv.z * invd, tv.w * invd};
        #pragma unroll
        for (int c = 0; c < 4; ++c) {
            ushort h = bf16_rne(f[c]);
            Thi[(wl + c) * 66 + j] = h;
            Tlo[(wl + c) * 66 + j] = bf16_rne(f[c] - bf16_to_f32(h));
        }
    }
    __syncthreads();
    {
        int wl = tid >> 2, jc = (tid & 3) * 16;
        size_t go = ((size_t)b * Ww + w0 + wl) * Nn + j0 + jc;
        uint tH[8], tL[8];
        #pragma unroll
        for (int u = 0; u < 8; ++u) {
            tH[u] = *(const uint*)&Thi[wl * 66 + jc + u * 2];
            tL[u] = *(const uint*)&Tlo[wl * 66 + jc + u * 2];
        }
        #pragma unroll
        for (int u = 0; u < 2; ++u) {
            uint4 hh; hh.x = tH[u*4+0]; hh.y = tH[u*4+1]; hh.z = tH[u*4+2]; hh.w = tH[u*4+3];
            uint4 ll; ll.x = tL[u*4+0]; ll.y = tL[u*4+1]; ll.z = tL[u*4+2]; ll.w = tL[u*4+3];
            *(uint4*)(vthi + go + u * 8) = hh;
            *(uint4*)(vtlo + go + u * 8) = ll;
        }
    }
}

// ---------------------------------------------------------------------------
// Kernel 3: PV retiled 128i x 128w. part[kz] = sum_{j in kz-half} E·v'.
// 32 MFMA per K-step per wave (was 16): 4 waves 2x2, wave tile 64x64.
// Staging 6 bf16x8/thread (A row + Bh row + Bl row halves). Stride-40 rows
// (proven conflict-free), T14 prefetch, ksplit 2 direct stores.
// grid (16 i, 2 wt x 2 kz, 8 b) = 512 blocks. LDS 30 KB.
// ---------------------------------------------------------------------------
__global__ __launch_bounds__(256) void pv_mfma_kernel(
    const ushort* __restrict__ eh,
    const ushort* __restrict__ vthi, const ushort* __restrict__ vtlo,
    float* __restrict__ part)
{
    __shared__ alignas(16) ushort Ah[128*40];             // E tile  [i][j]
    __shared__ alignas(16) ushort Bh[128*40], Bl[128*40]; // v' tile [w][j]

    const int tid = threadIdx.x;
    const int i0 = blockIdx.x * 128;
    const int wt = blockIdx.y & 1, kz = blockIdx.y >> 1;
    const int w0 = wt * 128;
    const int b  = blockIdx.z;

    const ushort* ehb = eh + (size_t)b * Nn * Nn;
    const ushort* vhb = vthi + (size_t)b * Ww * Nn;
    const ushort* vlb = vtlo + (size_t)b * Ww * Nn;

    const int wave = tid >> 6, lane = tid & 63;
    const int wy = wave >> 1, wx = wave & 1;    // i-half / w-half (64 each)
    const int lr = lane & 15, lg = lane >> 4;

    f32x4 acc[4][4];
    #pragma unroll
    for (int a = 0; a < 4; ++a)
        #pragma unroll
        for (int c = 0; c < 4; ++c) acc[a][c] = (f32x4){0.f, 0.f, 0.f, 0.f};

    // staging: thread t -> row t>>1 (0..127), j-chunk (t&1)*16; 2 bf16x8 each
    // from A, Bh, Bl at the same (row, jc).
    const int srow = tid >> 1;
    const int sjc  = (tid & 1) * 16;
    const size_t aoff0 = (size_t)(i0 + srow) * Nn + (size_t)kz * 1024 + sjc;
    const size_t boff0 = (size_t)(w0 + srow) * Nn + (size_t)kz * 1024 + sjc;
    const int lbase = srow * 40 + sjc;

    // T14 prologue: tile 0
    bf16x8 ra0 = *(const bf16x8*)(ehb + aoff0);
    bf16x8 ra1 = *(const bf16x8*)(ehb + aoff0 + 8);
    bf16x8 rh0 = *(const bf16x8*)(vhb + boff0);
    bf16x8 rh1 = *(const bf16x8*)(vhb + boff0 + 8);
    bf16x8 rl0 = *(const bf16x8*)(vlb + boff0);
    bf16x8 rl1 = *(const bf16x8*)(vlb + boff0 + 8);

    for (int ks = 0; ks < 32; ++ks) {
        *(bf16x8*)&Ah[lbase]     = ra0;
        *(bf16x8*)&Ah[lbase + 8] = ra1;
        *(bf16x8*)&Bh[lbase]     = rh0;
        *(bf16x8*)&Bh[lbase + 8] = rh1;
        *(bf16x8*)&Bl[lbase]     = rl0;
        *(bf16x8*)&Bl[lbase + 8] = rl1;
        __syncthreads();

        if (ks < 31) {
            const size_t ao = aoff0 + (ks + 1) * 32;
            const size_t bo = boff0 + (ks + 1) * 32;
            ra0 = *(const bf16x8*)(ehb + ao);
            ra1 = *(const bf16x8*)(ehb + ao + 8);
            rh0 = *(const bf16x8*)(vhb + bo);
            rh1 = *(const bf16x8*)(vhb + bo + 8);
            rl0 = *(const bf16x8*)(vlb + bo);
            rl1 = *(const bf16x8*)(vlb + bo + 8);
        }

        bf16x8 af[4], bfh[4], bfl[4];
        #pragma unroll
        for (int t = 0; t < 4; ++t) {
            af[t] = *(const bf16x8*)&Ah[(wy * 64 + t * 16 + lr) * 40 + lg * 8];
            const int br = (wx * 64 + t * 16 + lr) * 40 + lg * 8;
            bfh[t] = *(const bf16x8*)&Bh[br];
            bfl[t] = *(const bf16x8*)&Bl[br];
        }
        #pragma unroll
        for (int ia = 0; ia < 4; ++ia)
            #pragma unroll
            for (int ib = 0; ib < 4; ++ib) {
                acc[ia][ib] = __builtin_amdgcn_mfma_f32_16x16x32_bf16(af[ia], bfh[ib], acc[ia][ib], 0, 0, 0);
                acc[ia][ib] = __builtin_amdgcn_mfma_f32_16x16x32_bf16(af[ia], bfl[ib], acc[ia][ib], 0, 0, 0);
            }
        __syncthreads();
    }

    float* pout = part + (size_t)kz * Mtot * Ww;
    #pragma unroll
    for (int ia = 0; ia < 4; ++ia) {
        const int ibase = i0 + wy * 64 + ia * 16 + lg * 4;
        #pragma unroll
        for (int ib = 0; ib < 4; ++ib) {
            const int w = w0 + wx * 64 + ib * 16 + lr;
            #pragma unroll
            for (int rg = 0; rg < 4; ++rg)
                pout[((size_t)(b * Nn + ibase + rg)) * Ww + w] = acc[ia][ib][rg];
        }
    }
}

// ---------------------------------------------------------------------------
// Kernel 4: out = part0 + part1 + q (q from split bf16). grid 4096, blk 256.
// ---------------------------------------------------------------------------
__global__ __launch_bounds__(256) void qadd_kernel(
    const float* __restrict__ part,
    const ushort* __restrict__ qhi, const ushort* __restrict__ qlo,
    float* __restrict__ out)
{
    const size_t g4 = ((size_t)blockIdx.x * 256 + threadIdx.x) * 4;
    float4 p0 = *(const float4*)(part + g4);
    float4 p1 = *(const float4*)(part + (size_t)Mtot * Ww + g4);
    ushort4 h = *(const ushort4*)(qhi + g4);
    ushort4 l = *(const ushort4*)(qlo + g4);
    float4 o;
    o.x = p0.x + p1.x + bf16_to_f32(h.x) + bf16_to_f32(l.x);
    o.y = p0.y + p1.y + bf16_to_f32(h.y) + bf16_to_f32(l.y);
    o.z = p0.z + p1.z + bf16_to_f32(h.z) + bf16_to_f32(l.z);
    o.w = p0.w + p1.w + bf16_to_f32(h.w) + bf16_to_f32(l.w);
    *(float4*)(out + g4) = o;
}

// ---------------------------------------------------------------------------
// Launch. ws: v32 f32 [16MB] | qhi,qlo,khi,klo [32MB] | Eh [64MB] |
// part [32MB] | Dp [64KB] | xh,xl [16MB] | W splits [0.75MB] = ~161 MiB.
// vthi/vtlo reuse khi/klo after scores consumed k.
// ---------------------------------------------------------------------------
extern "C" void kernel_launch(void* const* d_in, const int* in_sizes, int n_in,
                              void* d_out, int out_size, void* d_ws, size_t ws_size,
                              hipStream_t stream) {
    const float* x  = (const float*)d_in[0];
    const float* Wq = (const float*)d_in[1];
    const float* bq = (const float*)d_in[2];
    const float* Wk = (const float*)d_in[3];
    const float* bk = (const float*)d_in[4];
    const float* Wv = (const float*)d_in[5];
    const float* bv = (const float*)d_in[6];
    // d_in[7] = valid_len (unused by the reference forward)
    float* out = (float*)d_out;

    float*  v32 = (float*)d_ws;
    ushort* qhi = (ushort*)(v32 + (size_t)Mtot * Ww);
    ushort* qlo = qhi + (size_t)Mtot * Ww;
    ushort* khi = qlo + (size_t)Mtot * Ww;
    ushort* klo = khi + (size_t)Mtot * Ww;
    ushort* eh  = klo + (size_t)Mtot * Ww;
    float*  part = (float*)(eh + (size_t)Bb * Nn * Nn);
    float*  dpart = part + (size_t)2 * Mtot * Ww;
    ushort* xh  = (ushort*)(dpart + Bb * Nn);
    ushort* xl  = xh + (size_t)Mtot * Cc;
    ushort* wqh = xl + (size_t)Mtot * Cc;
    ushort* wql = wqh + Ww * Cc;
    ushort* wkh = wql + Ww * Cc;
    ushort* wkl = wkh + Ww * Cc;
    ushort* wvh = wkl + Ww * Cc;
    ushort* wvl = wvh + Ww * Cc;
    ushort* vthi = khi;   // reuse after scores_mfma consumed k
    ushort* vtlo = klo;

    hipMemsetAsync(dpart, 0, (size_t)Bb * Nn * sizeof(float), stream);
    prep_kernel<<<dim3(4288), 256, 0, stream>>>(x, Wq, Wk, Wv, xh, xl,
                                                wqh, wql, wkh, wkl, wvh, wvl);
    qkv_mfma_kernel<<<dim3(128, 6), 256, 0, stream>>>(xh, xl, wqh, wql, wkh, wkl,
                                                      wvh, wvl, bq, bk, bv,
                                                      v32, qhi, qlo, khi, klo);
    scores_mfma_kernel<<<dim3(16, 16, 8), 256, 0, stream>>>(qhi, qlo, khi, klo, eh, dpart);
    vt_kernel<<<dim3(32, 4, 8), 256, 0, stream>>>(v32, dpart, vthi, vtlo);
    pv_mfma_kernel<<<dim3(16, 4, 8), 256, 0, stream>>>(eh, vthi, vtlo, part);
    qadd_kernel<<<dim3(4096), 256, 0, stream>>>(part, qhi, qlo, out);
}